// Round 18
// baseline (591.796 us; speedup 1.0000x reference)
//
#include <hip/hip_runtime.h>
#include <hip/hip_bf16.h>

typedef unsigned int u32;
typedef unsigned short u16;

#define DF __device__ __forceinline__

DF float bf2f(u16 v){ u32 t = ((u32)v)<<16; return __builtin_bit_cast(float, t); }
DF u16 f2bf(float f){
  u32 t = __builtin_bit_cast(u32, f);
  t += 0x7fffu + ((t>>16)&1u);
  return (u16)(t>>16);
}
DF float lo16(u32 p){ return __builtin_bit_cast(float, p<<16); }
DF float hi16(u32 p){ return __builtin_bit_cast(float, p & 0xffff0000u); }
DF u32 pack2(float a, float b){ return (u32)f2bf(a) | (((u32)f2bf(b))<<16); }
DF float gelu(float x){ return 0.5f*x*(1.0f+erff(x*0.70710678118654752f)); }

typedef __attribute__((ext_vector_type(8))) __bf16 bf16x8;
typedef __attribute__((ext_vector_type(4))) __bf16 bf16x4;
typedef __attribute__((ext_vector_type(4))) float f32x4;

// 16x16x16 bf16 MFMA wrapper (name varies across toolchains)
#if defined(__has_builtin)
#if __has_builtin(__builtin_amdgcn_mfma_f32_16x16x16_bf16)
#define MFMA16_OK 1
DF f32x4 mfma16(bf16x4 a, bf16x4 b, f32x4 c){
  return __builtin_amdgcn_mfma_f32_16x16x16_bf16(a, b, c, 0, 0, 0);
}
#elif __has_builtin(__builtin_amdgcn_mfma_f32_16x16x16bf16_1k)
#define MFMA16_OK 1
typedef __attribute__((ext_vector_type(4))) short s16x4;
DF f32x4 mfma16(bf16x4 a, bf16x4 b, f32x4 c){
  return __builtin_amdgcn_mfma_f32_16x16x16bf16_1k(
      __builtin_bit_cast(s16x4, a), __builtin_bit_cast(s16x4, b), c, 0, 0, 0);
}
#endif
#endif
#ifndef MFMA16_OK
DF f32x4 mfma16(bf16x4 a, bf16x4 b, f32x4 c){
  f32x4 d;
  asm("v_mfma_f32_16x16x16_bf16 %0, %1, %2, %3" : "=v"(d) : "v"(a), "v"(b), "v"(c));
  return d;
}
#endif

// ---------------------------------------------------------------------------
// K0: pack qkv/proj weights as MFMA B-fragments (front of d_out).
// ---------------------------------------------------------------------------
__global__ void wprep_k(const float* __restrict__ qkvw, const float* __restrict__ projw,
                        u32* __restrict__ w8q, u32* __restrict__ w8p)
{
  int e = blockIdx.x*256 + threadIdx.x;
  if (e < 13824){
    int jk = e >> 8, lane = (e >> 2) & 63, q = e & 3;
    int jt = jk/3, ks = jk - jt*3;
    int n = jt*16 + (lane & 15);
    int k = ks*32 + (lane >> 4)*8 + 2*q;
    w8q[e] = pack2(qkvw[n*96 + k], qkvw[n*96 + k + 1]);
  } else if (e < 18432){
    int r2 = e - 13824;
    int jk = r2 >> 8, lane = (r2 >> 2) & 63, q = r2 & 3;
    int jt = jk/3, ks = jk - jt*3;
    int n = jt*16 + (lane & 15);
    int k = ks*32 + (lane >> 4)*8 + 2*q;
    w8p[r2] = pack2(projw[n*96 + k], projw[n*96 + k + 1]);
  }
}

// ---------------------------------------------------------------------------
// K0b: conv weights as MFMA B-fragments into ws tail.
// ---------------------------------------------------------------------------
__global__ void wprep_cv(const float* __restrict__ c1w, const float* __restrict__ c2w,
                         u32* __restrict__ wcv)
{
  int e = blockIdx.x*256 + threadIdx.x;
  if (e >= 82944) return;
  int conv = e / 41472, r = e - conv*41472;
  int tap = r / 4608, r2 = r - tap*4608;
  int jk = r2 >> 8;
  int lane = (r2 >> 2) & 63;
  int q = r2 & 3;
  int j = jk/3, ks = jk - j*3;
  int n = j*16 + (lane & 15);
  int k = ks*32 + (lane >> 4)*8 + 2*q;
  const float* s = conv ? c2w : c1w;
  wcv[e] = pack2(s[(n*96 + k)*9 + tap], s[(n*96 + k + 1)*9 + tap]);
}

// ---------------------------------------------------------------------------
// K0c: mlp w1/w2 as MFMA B-fragments into ws tail (after wcv).
// ---------------------------------------------------------------------------
__global__ void wprep_m(const float* __restrict__ w1, const float* __restrict__ w2,
                        u32* __restrict__ wm)
{
  int e = blockIdx.x*256 + threadIdx.x;
  if (e >= 36864) return;
  int which = e / 18432, r = e - which*18432;
  int q = r / 4608, r2 = r - q*4608;
  int jk = r2 >> 8, lane = (r2 >> 2) & 63, qq = r2 & 3;
  int jt = jk/3, ks = jk - jt*3;
  int n = jt*16 + (lane & 15);
  int k = ks*32 + (lane >> 4)*8 + 2*qq;
  if (which == 0){
    const float* s = w1 + (size_t)(q*96 + n)*96 + k;
    wm[e] = pack2(s[0], s[1]);
  } else {
    const float* s = w2 + (size_t)n*384 + q*96 + k;
    wm[e] = pack2(s[0], s[1]);
  }
}

// ---------------------------------------------------------------------------
// K1: fused windowed attention — full-MFMA (QKV, QK^T, PV, proj).
// qS FULLY zero-initialized (R17 NaN fix: A-side pad reads must be finite;
// NaN*0 = NaN poisoned the S matrix through uninit row padding).
// LDS ~67.8KB -> 2 blocks/CU.
// ---------------------------------------------------------------------------
__global__ __launch_bounds__(256,2) void attn_k(
    const float* __restrict__ x, const float* __restrict__ ndwi,
    const float* __restrict__ n1g, const float* __restrict__ n1b,
    const u32* __restrict__ w8q, const float* __restrict__ qb,
    const u32* __restrict__ w8p, const float* __restrict__ pb,
    const float* __restrict__ rpbt, u16* __restrict__ x1o)
{
  __shared__ __align__(16) u16 xA[4*3*64*8];   // 12KB: x A-frags; later attn-out A-frags
  __shared__ __align__(16) u16 qS[64*100];     // 12.8KB: q rows; later proj-out rows
  __shared__ __align__(16) u16 kB[8*4*64*4];   // 16KB: K B-frags (16x16x16), zero-padded
  __shared__ __align__(16) u16 vB[8*4*64*4];   // 16KB: V B-frags, zero-padded
  __shared__ __align__(16) u16 pS[4*16*68];    // 8.7KB: per-wave P scratch
  __shared__ u16 rpb16[8*169];
  __shared__ float mw[49];
  const int tid = threadIdx.x;
  const int blk = blockIdx.x;
  const int b = blk >> 10, wy = (blk>>5)&31, wx = blk&31;
  const int wv_ = __builtin_amdgcn_readfirstlane(tid >> 6);
  const int ln  = tid & 63;
  const int colv = ln & 15, rgrp = ln >> 4;

  for (int i = tid; i < 1352; i += 256){
    int h = i/169, idx = i - h*169;
    rpb16[i] = f2bf(rpbt[idx*8 + h]);
  }
  for (int i = tid; i < 4096; i += 256){ ((u32*)kB)[i] = 0; ((u32*)vB)[i] = 0; }
  for (int i = tid; i < 3200; i += 256) ((u32*)qS)[i] = 0;   // R17 fix

  // LN1 straight from global -> xA fragments (4 lanes per token)
  if (tid < 196){
    const int t = tid >> 2, p = tid & 3;
    const int ty = t/7, tx = t - (t/7)*7;
    int sy = wy*7 + ty - 3; if (sy < 0) sy += 224;
    int sx = wx*7 + tx - 3; if (sx < 0) sx += 224;
    const size_t rowb = ((size_t)((b*224 + sy)*224 + sx))*96;
    const float* xr = x + rowb + p*24;
    float c[24];
    #pragma unroll
    for (int q = 0; q < 6; q++){
      float4 v = ((const float4*)xr)[q];
      c[q*4+0]=v.x; c[q*4+1]=v.y; c[q*4+2]=v.z; c[q*4+3]=v.w;
    }
    if (p == 0) mw[t] = ndwi[(size_t)b*50176 + sy*224 + sx];
    float s = 0.f, s2 = 0.f;
    #pragma unroll
    for (int j = 0; j < 24; j++){ s += c[j]; s2 += c[j]*c[j]; }
    s  += __shfl_xor(s, 1);  s  += __shfl_xor(s, 2);
    s2 += __shfl_xor(s2, 1); s2 += __shfl_xor(s2, 2);
    float m = s*(1.f/96.f);
    float rs = rsqrtf(s2*(1.f/96.f) - m*m + 1e-5f);
    const int mt = t >> 4, row = t & 15;
    #pragma unroll
    for (int jj = 0; jj < 12; jj++){
      int k = p*24 + 2*jj;
      float a = (c[2*jj]  -m)*rs*n1g[k]   + n1b[k];
      float d = (c[2*jj+1]-m)*rs*n1g[k+1] + n1b[k+1];
      int ks = k >> 5, g = (k & 31) >> 3, i = k & 7;
      *(u32*)&xA[(((mt*3 + ks)*64 + g*16 + row)<<3) + i] = pack2(a, d);
    }
  }
  __syncthreads();

  // QKV via MFMA (K=32 frags); scatter q->rows, k/v->B-fragments
  {
    bf16x8 af[3];
    #pragma unroll
    for (int ks = 0; ks < 3; ks++)
      af[ks] = *(const bf16x8*)&xA[((wv_*3 + ks)*64 + ln)*8];
    const float S = 0.28867513459481287f;
    for (int jt = 0; jt < 18; jt++){
      f32x4 c = (f32x4){0.f,0.f,0.f,0.f};
      #pragma unroll
      for (int ks = 0; ks < 3; ks++){
        bf16x8 bw = *(const bf16x8*)(w8q + ((jt*3 + ks)*64 + ln)*4);
        c = __builtin_amdgcn_mfma_f32_16x16x32_bf16(af[ks], bw, c, 0, 0, 0);
      }
      const int oc = jt*16 + colv;
      const float bv = qb[oc];
      #pragma unroll
      for (int r = 0; r < 4; r++){
        int tok = wv_*16 + rgrp*4 + r;
        if (tok < 49){
          float v = c[r] + bv;
          if (oc < 96){
            qS[tok*100 + oc] = f2bf(v*S);
          } else if (oc < 192){
            int ock = oc - 96, h = ock/12, kd = ock - h*12;
            kB[((h*4 + (tok>>4))*64 + (kd>>2)*16 + (tok&15))*4 + (kd&3)] = f2bf(v);
          } else {
            int ocv = oc - 192, h = ocv/12, d = ocv - h*12;
            vB[((h*4 + (tok>>4))*64 + ((tok&15)>>2)*16 + d)*4 + (tok&3)] = f2bf(v);
          }
        }
      }
    }
  }
  __syncthreads();

  // MFMA attention core: wave handles heads wv_ and wv_+4.
  {
    int jyv[4], jxv[4]; float mwj[4]; bool jok[4];
    #pragma unroll
    for (int nt = 0; nt < 4; nt++){
      int j = nt*16 + colv;
      jok[nt] = (j < 49);
      int jc = jok[nt] ? j : 48;
      jyv[nt] = jc/7; jxv[nt] = jc - 7*jyv[nt];
      mwj[nt] = mw[jc];
    }
    u16* pw = pS + wv_*(16*68);
    for (int hh = 0; hh < 2; hh++){
      const int h = wv_ + hh*4;
      for (int mt = 0; mt < 4; mt++){
        bf16x4 aq = *(const bf16x4*)&qS[(mt*16 + (ln&15))*100 + h*12 + (ln>>4)*4];
        f32x4 Sm[4];
        #pragma unroll
        for (int nt = 0; nt < 4; nt++)
          Sm[nt] = mfma16(aq, *(const bf16x4*)&kB[((h*4 + nt)*64 + ln)*4],
                          (f32x4){0.f,0.f,0.f,0.f});
        // softmax per row (reduction over the 16-lane col group)
        #pragma unroll
        for (int r = 0; r < 4; r++){
          int i = mt*16 + rgrp*4 + r;
          int ic = i < 49 ? i : 48;
          int iy = ic/7, ix = ic - 7*iy;
          float mi = mw[ic];
          float val[4]; float mx = -3e38f;
          #pragma unroll
          for (int nt = 0; nt < 4; nt++){
            float a = Sm[nt][r] + bf2f(rpb16[h*169 + (iy - jyv[nt] + 6)*13 + (ix - jxv[nt] + 6)]);
            a = (mi != mwj[nt]) ? a - 100.f : a;
            a = jok[nt] ? a : -3e38f;
            val[nt] = a; mx = fmaxf(mx, a);
          }
          mx = fmaxf(mx, __shfl_xor(mx, 1));
          mx = fmaxf(mx, __shfl_xor(mx, 2));
          mx = fmaxf(mx, __shfl_xor(mx, 4));
          mx = fmaxf(mx, __shfl_xor(mx, 8));
          float p[4]; float l = 0.f;
          #pragma unroll
          for (int nt = 0; nt < 4; nt++){ p[nt] = __expf(val[nt]-mx); l += p[nt]; }
          l += __shfl_xor(l, 1); l += __shfl_xor(l, 2);
          l += __shfl_xor(l, 4); l += __shfl_xor(l, 8);
          float rl = 1.f/l;
          #pragma unroll
          for (int nt = 0; nt < 4; nt++)
            pw[(rgrp*4 + r)*68 + nt*16 + colv] = f2bf(p[nt]*rl);
        }
        asm volatile("" ::: "memory");
        // PV
        f32x4 O = (f32x4){0.f,0.f,0.f,0.f};
        #pragma unroll
        for (int ks = 0; ks < 4; ks++){
          bf16x4 aP = *(const bf16x4*)&pw[(ln&15)*68 + ks*16 + (ln>>4)*4];
          O = mfma16(aP, *(const bf16x4*)&vB[((h*4 + ks)*64 + ln)*4], O);
        }
        asm volatile("" ::: "memory");
        // store O -> xA A-frag slots (channel c = h*12+colv)
        if (colv < 12){
          int cch = h*12 + colv;
          int ks2 = cch >> 5, g2 = (cch & 31) >> 3, ii = cch & 7;
          #pragma unroll
          for (int r = 0; r < 4; r++){
            int tok = mt*16 + rgrp*4 + r;
            if (tok < 49)
              xA[(((mt*3 + ks2)*64 + g2*16 + (tok&15))<<3) + ii] = f2bf(O[r]);
          }
        }
      }
    }
  }
  __syncthreads();

  // proj via MFMA -> qS rows (dead after core)
  {
    bf16x8 af[3];
    #pragma unroll
    for (int ks = 0; ks < 3; ks++)
      af[ks] = *(const bf16x8*)&xA[((wv_*3 + ks)*64 + ln)*8];
    for (int jt = 0; jt < 6; jt++){
      f32x4 c = (f32x4){0.f,0.f,0.f,0.f};
      #pragma unroll
      for (int ks = 0; ks < 3; ks++){
        bf16x8 bw = *(const bf16x8*)(w8p + ((jt*3 + ks)*64 + ln)*4);
        c = __builtin_amdgcn_mfma_f32_16x16x32_bf16(af[ks], bw, c, 0, 0, 0);
      }
      const int oc = jt*16 + colv;
      const float bv = pb[oc];
      #pragma unroll
      for (int r = 0; r < 4; r++){
        int tok = wv_*16 + rgrp*4 + r;
        if (tok < 49) qS[tok*100 + oc] = f2bf(c[r] + bv);
      }
    }
  }
  __syncthreads();

  // write: reverse roll (-4) + residual
  const u32* qS32 = (const u32*)qS;
  for (int e = tid; e < 588; e += 256){
    int t = e/12, g = e - (e/12)*12;
    int ty = t/7, tx = t - (t/7)*7;
    int dy = wy*7 + ty - 4; if (dy < 0) dy += 224;
    int dx = wx*7 + tx - 4; if (dx < 0) dx += 224;
    size_t base = ((size_t)((b*224+dy)*224+dx))*96 + g*8;
    float4 r0 = *(const float4*)(x + base);
    float4 r1 = *(const float4*)(x + base + 4);
    const u32* pr = &qS32[t*50 + g*4];
    uint4 ov;
    ov.x = pack2(lo16(pr[0])+r0.x, hi16(pr[0])+r0.y);
    ov.y = pack2(lo16(pr[1])+r0.z, hi16(pr[1])+r0.w);
    ov.z = pack2(lo16(pr[2])+r1.x, hi16(pr[2])+r1.y);
    ov.w = pack2(lo16(pr[3])+r1.z, hi16(pr[3])+r1.w);
    *(uint4*)(x1o + base) = ov;
  }
}

// ---------------------------------------------------------------------------
// K2a: MLP, B-fragments direct from global (unchanged from R16).
// ---------------------------------------------------------------------------
__global__ __launch_bounds__(256,4) void mlp_direct_k(
    const u16* __restrict__ x1, const u32* __restrict__ wm,
    const float* __restrict__ b1, const float* __restrict__ b2,
    const float* __restrict__ g2, const float* __restrict__ bb2,
    float* __restrict__ x2o)
{
  __shared__ __align__(16) u16 xA[4*3*64*8];
  __shared__ __align__(16) u16 hA[4*3*64*8];
  const int tid = threadIdx.x;
  const size_t t0 = (size_t)blockIdx.x * 64;
  const int wvM = tid >> 6;
  const int ln  = tid & 63;
  const int colv = ln & 15, rgrp = ln >> 4;
  const u32* w1m = wm;
  const u32* w2m = wm + 18432;

  {
    const int t = tid >> 2, p = tid & 3;
    const u16* xr = x1 + (t0 + t)*96 + p*24;
    float c[24];
    #pragma unroll
    for (int q = 0; q < 3; q++){
      uint4 v = ((const uint4*)xr)[q];
      c[q*8+0]=lo16(v.x); c[q*8+1]=hi16(v.x);
      c[q*8+2]=lo16(v.y); c[q*8+3]=hi16(v.y);
      c[q*8+4]=lo16(v.z); c[q*8+5]=hi16(v.z);
      c[q*8+6]=lo16(v.w); c[q*8+7]=hi16(v.w);
    }
    float s = 0.f, s2 = 0.f;
    #pragma unroll
    for (int j = 0; j < 24; j++){ s += c[j]; s2 += c[j]*c[j]; }
    s  += __shfl_xor(s, 1);  s  += __shfl_xor(s, 2);
    s2 += __shfl_xor(s2, 1); s2 += __shfl_xor(s2, 2);
    float m = s*(1.f/96.f);
    float rs = rsqrtf(s2*(1.f/96.f) - m*m + 1e-5f);
    const int mt = t >> 4, row = t & 15;
    #pragma unroll
    for (int jj = 0; jj < 12; jj++){
      int k = p*24 + 2*jj;
      float a = (c[2*jj]  -m)*rs*g2[k]   + bb2[k];
      float d = (c[2*jj+1]-m)*rs*g2[k+1] + bb2[k+1];
      int ks = k >> 5, g = (k & 31) >> 3, i = k & 7;
      *(u32*)&xA[(((mt*3 + ks)*64 + g*16 + row)<<3) + i] = pack2(a, d);
    }
  }
  __syncthreads();

  bf16x8 af[3];
  #pragma unroll
  for (int ks = 0; ks < 3; ks++)
    af[ks] = *(const bf16x8*)&xA[((wvM*3 + ks)*64 + ln)*8];

  f32x4 acc2[6];
  #pragma unroll
  for (int j = 0; j < 6; j++) acc2[j] = (f32x4){0.f,0.f,0.f,0.f};

  for (int q = 0; q < 4; q++){
    __syncthreads();
    #pragma unroll
    for (int j = 0; j < 6; j++){
      f32x4 c = (f32x4){0.f,0.f,0.f,0.f};
      #pragma unroll
      for (int ks = 0; ks < 3; ks++){
        bf16x8 bfv = *(const bf16x8*)(w1m + ((q*18 + j*3 + ks)*64 + ln)*4);
        c = __builtin_amdgcn_mfma_f32_16x16x32_bf16(af[ks], bfv, c, 0, 0, 0);
      }
      const float bv = b1[q*96 + j*16 + colv];
      const int kq = j*16 + colv;
      const int ks2 = kq >> 5, gg = (kq & 31) >> 3, ii = kq & 7;
      u16* hdst = &hA[(((wvM*3 + ks2)*64 + gg*16)<<3) + ii];
      #pragma unroll
      for (int r = 0; r < 4; r++){
        int rowh = rgrp*4 + r;
        hdst[rowh*8] = f2bf(gelu(c[r] + bv));
      }
    }
    __syncthreads();

    bf16x8 hf[3];
    #pragma unroll
    for (int ks = 0; ks < 3; ks++)
      hf[ks] = *(const bf16x8*)&hA[((wvM*3 + ks)*64 + ln)*8];
    #pragma unroll
    for (int j = 0; j < 6; j++){
      #pragma unroll
      for (int ks = 0; ks < 3; ks++){
        bf16x8 bfv = *(const bf16x8*)(w2m + ((q*18 + j*3 + ks)*64 + ln)*4);
        acc2[j] = __builtin_amdgcn_mfma_f32_16x16x32_bf16(hf[ks], bfv, acc2[j], 0, 0, 0);
      }
    }
  }

  #pragma unroll
  for (int j = 0; j < 6; j++){
    const int oc = j*16 + colv;
    const float bv = b2[oc];
    #pragma unroll
    for (int r = 0; r < 4; r++){
      size_t tok = t0 + wvM*16 + rgrp*4 + r;
      x2o[tok*96 + oc] = acc2[j][r] + bv + bf2f(x1[tok*96 + oc]);
    }
  }
}

// ---------------------------------------------------------------------------
// K2b: MLP, staged fallback (R15-verified).
// ---------------------------------------------------------------------------
__global__ __launch_bounds__(256,2) void mlp_stage_k(
    const u16* __restrict__ x1, const float* __restrict__ w1, const float* __restrict__ b1,
    const float* __restrict__ w2, const float* __restrict__ b2,
    const float* __restrict__ g2, const float* __restrict__ bb2,
    float* __restrict__ x2o)
{
  __shared__ __align__(16) u16 xA [4*3*64*8];
  __shared__ __align__(16) u16 hA [4*3*64*8];
  __shared__ __align__(16) u16 w1f[6*3*64*8];
  __shared__ __align__(16) u16 w2f[6*3*64*8];
  const int tid = threadIdx.x;
  const size_t t0 = (size_t)blockIdx.x * 64;
  const int wvM = tid >> 6;
  const int ln  = tid & 63;
  const int colv = ln & 15, rgrp = ln >> 4;

  {
    const int t = tid >> 2, p = tid & 3;
    const u16* xr = x1 + (t0 + t)*96 + p*24;
    float c[24];
    #pragma unroll
    for (int q = 0; q < 3; q++){
      uint4 v = ((const uint4*)xr)[q];
      c[q*8+0]=lo16(v.x); c[q*8+1]=hi16(v.x);
      c[q*8+2]=lo16(v.y); c[q*8+3]=hi16(v.y);
      c[q*8+4]=lo16(v.z); c[q*8+5]=hi16(v.z);
      c[q*8+6]=lo16(v.w); c[q*8+7]=hi16(v.w);
    }
    float s = 0.f, s2 = 0.f;
    #pragma unroll
    for (int j = 0; j < 24; j++){ s += c[j]; s2 += c[j]*c[j]; }
    s  += __shfl_xor(s, 1);  s  += __shfl_xor(s, 2);
    s2 += __shfl_xor(s2, 1); s2 += __shfl_xor(s2, 2);
    float m = s*(1.f/96.f);
    float rs = rsqrtf(s2*(1.f/96.f) - m*m + 1e-5f);
    const int mt = t >> 4, row = t & 15;
    #pragma unroll
    for (int jj = 0; jj < 12; jj++){
      int k = p*24 + 2*jj;
      float a = (c[2*jj]  -m)*rs*g2[k]   + bb2[k];
      float d = (c[2*jj+1]-m)*rs*g2[k+1] + bb2[k+1];
      int ks = k >> 5, g = (k & 31) >> 3, i = k & 7;
      *(u32*)&xA[(((mt*3 + ks)*64 + g*16 + row)<<3) + i] = pack2(a, d);
    }
  }

  f32x4 acc2[6];
  #pragma unroll
  for (int j = 0; j < 6; j++) acc2[j] = (f32x4){0.f,0.f,0.f,0.f};

  for (int q = 0; q < 4; q++){
    __syncthreads();
    for (int e = tid; e < 4608; e += 256){
      int n = e/48, cp = e - (e/48)*48, k = cp*2;
      int ks = k >> 5, g = (k & 31) >> 3, i = k & 7;
      int fidx = ((((n>>4)*3 + ks)*64 + g*16 + (n&15))<<3) + i;
      {
        const float* s = w1 + (size_t)(q*96 + n)*96 + k;
        *(u32*)&w1f[fidx] = pack2(s[0], s[1]);
      }
      {
        const float* s = w2 + (size_t)n*384 + q*96 + k;
        *(u32*)&w2f[fidx] = pack2(s[0], s[1]);
      }
    }
    __syncthreads();

    bf16x8 af[3];
    #pragma unroll
    for (int ks = 0; ks < 3; ks++)
      af[ks] = *(const bf16x8*)&xA[((wvM*3 + ks)*64 + ln)*8];
    #pragma unroll
    for (int j = 0; j < 6; j++){
      f32x4 c = (f32x4){0.f,0.f,0.f,0.f};
      #pragma unroll
      for (int ks = 0; ks < 3; ks++){
        bf16x8 bfv = *(const bf16x8*)&w1f[((j*3 + ks)*64 + ln)*8];
        c = __builtin_amdgcn_mfma_f32_16x16x32_bf16(af[ks], bfv, c, 0, 0, 0);
      }
      const float bv = b1[q*96 + j*16 + colv];
      const int kq = j*16 + colv;
      const int ks2 = kq >> 5, gg = (kq & 31) >> 3, ii = kq & 7;
      u16* hdst = &hA[(((wvM*3 + ks2)*64 + gg*16)<<3) + ii];
      #pragma unroll
      for (int r = 0; r < 4; r++){
        int rowh = rgrp*4 + r;
        hdst[rowh*8] = f2bf(gelu(c[r] + bv));
      }
    }
    __syncthreads();

    bf16x8 hf[3];
    #pragma unroll
    for (int ks = 0; ks < 3; ks++)
      hf[ks] = *(const bf16x8*)&hA[((wvM*3 + ks)*64 + ln)*8];
    #pragma unroll
    for (int j = 0; j < 6; j++){
      #pragma unroll
      for (int ks = 0; ks < 3; ks++){
        bf16x8 bfv = *(const bf16x8*)&w2f[((j*3 + ks)*64 + ln)*8];
        acc2[j] = __builtin_amdgcn_mfma_f32_16x16x32_bf16(hf[ks], bfv, acc2[j], 0, 0, 0);
      }
    }
  }

  #pragma unroll
  for (int j = 0; j < 6; j++){
    const int oc = j*16 + colv;
    const float bv = b2[oc];
    #pragma unroll
    for (int r = 0; r < 4; r++){
      size_t tok = t0 + wvM*16 + rgrp*4 + r;
      x2o[tok*96 + oc] = acc2[j][r] + bv + bf2f(x1[tok*96 + oc]);
    }
  }
}

// ---------------------------------------------------------------------------
// K3: MFMA implicit-GEMM 3x3 conv (unchanged from R16).
// ---------------------------------------------------------------------------
template<int DIL, bool LN3, bool FINAL, bool WD>
__global__ __launch_bounds__(256,4) void convm_k(
    const void* __restrict__ srcv, const u32* __restrict__ wpk,
    const float* __restrict__ wOIHW,
    const float* __restrict__ cb, const float* __restrict__ bng, const float* __restrict__ bnb,
    const float* __restrict__ bnm, const float* __restrict__ bnv,
    const float* __restrict__ g3, const float* __restrict__ b3,
    const float* resid, void* dstv)
{
  constexpr int SY = 8 + 2*DIL, SX = 8 + 2*DIL, NPIX = SY*SX;
  __shared__ __align__(16) u16 inT[NPIX*104];
  const int tid = threadIdx.x;
  const int bx = blockIdx.x*8, by = blockIdx.y*8, b = blockIdx.z;
  const int gy0 = by - DIL, gx0 = bx - DIL;

  for (int e = tid; e < NPIX*48; e += 256){
    int p = e/48, c2 = e - (e/48)*48;
    int y = p/SX, xx = p - (p/SX)*SX;
    int gy = gy0+y, gx = gx0+xx;
    u32 v = 0;
    if (gy >= 0 && gy < 224 && gx >= 0 && gx < 224){
      size_t idx = ((size_t)((b*224+gy)*224+gx))*96 + c2*2;
      if (LN3){
        float2 rd = *(const float2*)((const float*)srcv + idx);
        v = pack2(rd.x, rd.y);
      } else {
        v = *(const u32*)((const u16*)srcv + idx);
      }
    }
    *(u32*)&inT[p*104 + c2*2] = v;
  }
  __syncthreads();
  if (LN3){
    if (tid < 2*NPIX){
      const int p = tid >> 1, half = tid & 1;
      int y = p/SX, xx = p - (p/SX)*SX;
      int gy = gy0+y, gx = gx0+xx;
      if (gy >= 0 && gy < 224 && gx >= 0 && gx < 224){
        u32* row = (u32*)&inT[p*104] + half*24;
        float c[48];
        #pragma unroll
        for (int i = 0; i < 24; i++){ u32 v = row[i]; c[2*i] = lo16(v); c[2*i+1] = hi16(v); }
        float s = 0.f, s2 = 0.f;
        #pragma unroll
        for (int i = 0; i < 48; i++){ s += c[i]; s2 += c[i]*c[i]; }
        s  += __shfl_xor(s, 1);
        s2 += __shfl_xor(s2, 1);
        float m = s*(1.f/96.f);
        float rs = rsqrtf(s2*(1.f/96.f) - m*m + 1e-5f);
        const int cbase = half*48;
        #pragma unroll
        for (int i = 0; i < 24; i++){
          float a = (c[2*i]  -m)*rs*g3[cbase+2*i]   + b3[cbase+2*i];
          float d = (c[2*i+1]-m)*rs*g3[cbase+2*i+1] + b3[cbase+2*i+1];
          row[i] = pack2(a, d);
        }
      }
    }
    __syncthreads();
  }

  const int wvM = tid >> 6, ln = tid & 63;
  const int colv = ln & 15, rgrp = ln >> 4;
  const int arow = ln & 15;
  const int aoy = wvM*2 + (arow >> 3), aox = arow & 7;

  f32x4 acc[6];
  #pragma unroll
  for (int j = 0; j < 6; j++) acc[j] = (f32x4){0.f,0.f,0.f,0.f};

  if constexpr (WD){
    #pragma unroll 3
    for (int tap = 0; tap < 9; tap++){
      const int ky = tap/3, kx = tap - (tap/3)*3;
      const int p_in = (aoy + ky*DIL)*SX + aox + kx*DIL;
      bf16x8 af[3];
      #pragma unroll
      for (int ks = 0; ks < 3; ks++)
        af[ks] = *(const bf16x8*)&inT[p_in*104 + ks*32 + rgrp*8];
      const u32* wt = wpk + tap*4608;
      #pragma unroll
      for (int j = 0; j < 6; j++){
        #pragma unroll
        for (int ks = 0; ks < 3; ks++){
          bf16x8 bfv = *(const bf16x8*)(wt + ((j*3 + ks)*64 + ln)*4);
          acc[j] = __builtin_amdgcn_mfma_f32_16x16x32_bf16(af[ks], bfv, acc[j], 0, 0, 0);
        }
      }
    }
  } else {
    __shared__ __align__(16) u32 wfr[4608];
    for (int tap = 0; tap < 9; tap++){
      const int ky = tap/3, kx = tap - (tap/3)*3;
      __syncthreads();
      for (int e = tid; e < 4608; e += 256){
        int jk = e >> 8, lane = (e >> 2) & 63, q = e & 3;
        int j = jk/3, ks = jk - j*3;
        int n = j*16 + (lane & 15);
        int k = ks*32 + (lane >> 4)*8 + 2*q;
        wfr[e] = pack2(wOIHW[(n*96 + k)*9 + tap], wOIHW[(n*96 + k + 1)*9 + tap]);
      }
      __syncthreads();
      const int p_in = (aoy + ky*DIL)*SX + aox + kx*DIL;
      bf16x8 af[3];
      #pragma unroll
      for (int ks = 0; ks < 3; ks++)
        af[ks] = *(const bf16x8*)&inT[p_in*104 + ks*32 + rgrp*8];
      #pragma unroll
      for (int j = 0; j < 6; j++){
        #pragma unroll
        for (int ks = 0; ks < 3; ks++){
          bf16x8 bfv = *(const bf16x8*)((const u16*)wfr + ((j*3 + ks)*64 + ln)*8);
          acc[j] = __builtin_amdgcn_mfma_f32_16x16x32_bf16(af[ks], bfv, acc[j], 0, 0, 0);
        }
      }
    }
  }

  #pragma unroll
  for (int j = 0; j < 6; j++){
    const int oc = j*16 + colv;
    const float sc = bng[oc]*rsqrtf(bnv[oc]+1e-5f);
    const float mm = bnm[oc], bb = bnb[oc], cbv = cb[oc];
    #pragma unroll
    for (int r = 0; r < 4; r++){
      const int rowm = rgrp*4 + r;
      const int gy = by + wvM*2 + (rowm >> 3), gx = bx + (rowm & 7);
      size_t idx = ((size_t)((b*224+gy)*224+gx))*96 + oc;
      float t = (acc[j][r] + cbv - mm)*sc + bb;
      float o = gelu(t);
      if (FINAL){
        ((float*)dstv)[idx] = o + resid[idx];
      } else {
        ((u16*)dstv)[idx] = f2bf(o);
      }
    }
  }
}

// ---------------------------------------------------------------------------
extern "C" void kernel_launch(void* const* d_in, const int* in_sizes, int n_in,
                              void* d_out, int out_size, void* d_ws, size_t ws_size,
                              hipStream_t stream)
{
  const float* x    = (const float*)d_in[0];
  const float* ndwi = (const float*)d_in[1];
  const float* n1g  = (const float*)d_in[2];
  const float* n1b  = (const float*)d_in[3];
  const float* qkvw = (const float*)d_in[4];
  const float* qkvb = (const float*)d_in[5];
  const float* projw= (const float*)d_in[6];
  const float* projb= (const float*)d_in[7];
  const float* rpbt = (const float*)d_in[8];
  const float* n2g  = (const float*)d_in[9];
  const float* n2b  = (const float*)d_in[10];
  const float* w1   = (const float*)d_in[11];
  const float* b1   = (const float*)d_in[12];
  const float* w2   = (const float*)d_in[13];
  const float* b2   = (const float*)d_in[14];
  const float* n3g  = (const float*)d_in[15];
  const float* n3b  = (const float*)d_in[16];
  const float* c1w  = (const float*)d_in[17];
  const float* c1b  = (const float*)d_in[18];
  const float* bn1g = (const float*)d_in[19];
  const float* bn1b = (const float*)d_in[20];
  const float* bn1m = (const float*)d_in[21];
  const float* bn1v = (const float*)d_in[22];
  const float* c2w  = (const float*)d_in[23];
  const float* c2b  = (const float*)d_in[24];
  const float* bn2g = (const float*)d_in[25];
  const float* bn2b = (const float*)d_in[26];
  const float* bn2m = (const float*)d_in[27];
  const float* bn2v = (const float*)d_in[28];

  int B = out_size / (224*224*96);
  if (B < 1 || B > 64) B = 4;
  const size_t elems = (size_t)B*224*224*96;

  u16*   wsA = (u16*)d_ws;
  u32*   w8q = (u32*)d_out;
  u32*   w8p = w8q + 13824;
  float* xo  = (float*)d_out;
  u32*   wcv = nullptr;
  u32*   wm  = nullptr;
  if (ws_size >= elems*sizeof(u16) + 82944*sizeof(u32))
    wcv = (u32*)(wsA + elems);
  if (ws_size >= elems*sizeof(u16) + (82944 + 36864)*sizeof(u32))
    wm = wcv + 82944;

  wprep_k<<<dim3(72), dim3(256), 0, stream>>>(qkvw, projw, w8q, w8p);
  if (wcv) wprep_cv<<<dim3(324), dim3(256), 0, stream>>>(c1w, c2w, wcv);
  if (wm)  wprep_m<<<dim3(144), dim3(256), 0, stream>>>(w1, w2, wm);
  attn_k<<<dim3(B*1024), dim3(256), 0, stream>>>(x, ndwi, n1g, n1b, w8q, qkvb, w8p, projb, rpbt, wsA);
  if (wm)
    mlp_direct_k<<<dim3(B*784), dim3(256), 0, stream>>>(wsA, wm, b1, b2, n2g, n2b, xo);
  else
    mlp_stage_k<<<dim3(B*784), dim3(256), 0, stream>>>(wsA, w1, b1, w2, b2, n2g, n2b, xo);
  if (wcv){
    convm_k<1,true ,false,true ><<<dim3(28,28,B), dim3(256), 0, stream>>>(
        xo,  wcv,        c1w, c1b, bn1g, bn1b, bn1m, bn1v, n3g, n3b, nullptr, wsA);
    convm_k<2,false,true ,true ><<<dim3(28,28,B), dim3(256), 0, stream>>>(
        wsA, wcv+41472,  c2w, c2b, bn2g, bn2b, bn2m, bn2v, nullptr, nullptr, xo, xo);
  } else {
    convm_k<1,true ,false,false><<<dim3(28,28,B), dim3(256), 0, stream>>>(
        xo,  nullptr,    c1w, c1b, bn1g, bn1b, bn1m, bn1v, n3g, n3b, nullptr, wsA);
    convm_k<2,false,true ,false><<<dim3(28,28,B), dim3(256), 0, stream>>>(
        wsA, nullptr,    c2w, c2b, bn2g, bn2b, bn2m, bn2v, nullptr, nullptr, xo, xo);
  }
}

// Round 19
// 555.441 us; speedup vs baseline: 1.0655x; 1.0655x over previous
//
#include <hip/hip_runtime.h>
#include <hip/hip_bf16.h>

typedef unsigned int u32;
typedef unsigned short u16;

#define DF __device__ __forceinline__

DF float bf2f(u16 v){ u32 t = ((u32)v)<<16; return __builtin_bit_cast(float, t); }
DF u16 f2bf(float f){
  u32 t = __builtin_bit_cast(u32, f);
  t += 0x7fffu + ((t>>16)&1u);
  return (u16)(t>>16);
}
DF float lo16(u32 p){ return __builtin_bit_cast(float, p<<16); }
DF float hi16(u32 p){ return __builtin_bit_cast(float, p & 0xffff0000u); }
DF u32 pack2(float a, float b){ return (u32)f2bf(a) | (((u32)f2bf(b))<<16); }
DF float gelu(float x){ return 0.5f*x*(1.0f+erff(x*0.70710678118654752f)); }

#if defined(__has_builtin)
#if __has_builtin(__builtin_amdgcn_fdot2_f32_bf16)
#define HAVE_DOT2 1
#endif
#endif
#ifdef HAVE_DOT2
DF float dot2bf(u32 a, u32 b, float c){
  typedef __bf16 b2 __attribute__((ext_vector_type(2)));
  return __builtin_amdgcn_fdot2_f32_bf16(__builtin_bit_cast(b2,a), __builtin_bit_cast(b2,b), c, false);
}
#else
DF float dot2bf(u32 a, u32 b, float c){
  float d;
  asm("v_dot2_f32_bf16 %0, %1, %2, %3" : "=v"(d) : "v"(a), "v"(b), "v"(c));
  return d;
}
#endif

typedef __attribute__((ext_vector_type(8))) __bf16 bf16x8;
typedef __attribute__((ext_vector_type(4))) float f32x4;

// ---------------------------------------------------------------------------
// K0: pack qkv/proj weights as MFMA B-fragments (front of d_out).
// ---------------------------------------------------------------------------
__global__ void wprep_k(const float* __restrict__ qkvw, const float* __restrict__ projw,
                        u32* __restrict__ w8q, u32* __restrict__ w8p)
{
  int e = blockIdx.x*256 + threadIdx.x;
  if (e < 13824){
    int jk = e >> 8, lane = (e >> 2) & 63, q = e & 3;
    int jt = jk/3, ks = jk - jt*3;
    int n = jt*16 + (lane & 15);
    int k = ks*32 + (lane >> 4)*8 + 2*q;
    w8q[e] = pack2(qkvw[n*96 + k], qkvw[n*96 + k + 1]);
  } else if (e < 18432){
    int r2 = e - 13824;
    int jk = r2 >> 8, lane = (r2 >> 2) & 63, q = r2 & 3;
    int jt = jk/3, ks = jk - jt*3;
    int n = jt*16 + (lane & 15);
    int k = ks*32 + (lane >> 4)*8 + 2*q;
    w8p[r2] = pack2(projw[n*96 + k], projw[n*96 + k + 1]);
  }
}

// ---------------------------------------------------------------------------
// K0b: conv weights as MFMA B-fragments into ws tail.
// ---------------------------------------------------------------------------
__global__ void wprep_cv(const float* __restrict__ c1w, const float* __restrict__ c2w,
                         u32* __restrict__ wcv)
{
  int e = blockIdx.x*256 + threadIdx.x;
  if (e >= 82944) return;
  int conv = e / 41472, r = e - conv*41472;
  int tap = r / 4608, r2 = r - tap*4608;
  int jk = r2 >> 8;
  int lane = (r2 >> 2) & 63;
  int q = r2 & 3;
  int j = jk/3, ks = jk - j*3;
  int n = j*16 + (lane & 15);
  int k = ks*32 + (lane >> 4)*8 + 2*q;
  const float* s = conv ? c2w : c1w;
  wcv[e] = pack2(s[(n*96 + k)*9 + tap], s[(n*96 + k + 1)*9 + tap]);
}

// ---------------------------------------------------------------------------
// K0c: mlp w1/w2 as MFMA B-fragments into ws tail (after wcv).
// ---------------------------------------------------------------------------
__global__ void wprep_m(const float* __restrict__ w1, const float* __restrict__ w2,
                        u32* __restrict__ wm)
{
  int e = blockIdx.x*256 + threadIdx.x;
  if (e >= 36864) return;
  int which = e / 18432, r = e - which*18432;
  int q = r / 4608, r2 = r - q*4608;
  int jk = r2 >> 8, lane = (r2 >> 2) & 63, qq = r2 & 3;
  int jt = jk/3, ks = jk - jt*3;
  int n = jt*16 + (lane & 15);
  int k = ks*32 + (lane >> 4)*8 + 2*qq;
  if (which == 0){
    const float* s = w1 + (size_t)(q*96 + n)*96 + k;
    wm[e] = pack2(s[0], s[1]);
  } else {
    const float* s = w2 + (size_t)n*384 + q*96 + k;
    wm[e] = pack2(s[0], s[1]);
  }
}

// ---------------------------------------------------------------------------
// K1: fused windowed attention — MFMA QKV/proj + dot2 softmax core.
// (R16-verified: 232us, 3 blocks/CU, 43KB LDS. R18's MFMA core regressed
// to 269us via occupancy loss; reverted.)
// ---------------------------------------------------------------------------
__global__ __launch_bounds__(256,3) void attn_k(
    const float* __restrict__ x, const float* __restrict__ ndwi,
    const float* __restrict__ n1g, const float* __restrict__ n1b,
    const u32* __restrict__ w8q, const float* __restrict__ qb,
    const u32* __restrict__ w8p, const float* __restrict__ pb,
    const float* __restrict__ rpbt, u16* __restrict__ x1o)
{
  __shared__ __align__(16) u16 xA[4*3*64*8];  // x A-frags; later attn-out A-frags
  __shared__ u32 qp[49*49];    // q as u16[49][98]; later proj-out
  __shared__ u32 kp[49*49];    // k as u16[49][98]
  __shared__ u16 vpT[96*50];   // v transposed [d][j]
  __shared__ float rpb[8*169];
  __shared__ float mw[49];
  const int tid = threadIdx.x;
  const int blk = blockIdx.x;
  const int b = blk >> 10, wy = (blk>>5)&31, wx = blk&31;
  const int wv_ = __builtin_amdgcn_readfirstlane(tid >> 6);
  const int ln  = tid & 63;
  const int colv = ln & 15, rgrp = ln >> 4;

  for (int i = tid; i < 1352; i += 256){
    int h = i/169, idx = i - h*169;
    rpb[i] = rpbt[idx*8 + h];
  }
  for (int i = tid; i < 96; i += 256) vpT[i*50 + 49] = 0;

  // LN1 straight from global -> xA fragments (4 lanes per token)
  if (tid < 196){
    const int t = tid >> 2, p = tid & 3;
    const int ty = t/7, tx = t - (t/7)*7;
    int sy = wy*7 + ty - 3; if (sy < 0) sy += 224;
    int sx = wx*7 + tx - 3; if (sx < 0) sx += 224;
    const size_t rowb = ((size_t)((b*224 + sy)*224 + sx))*96;
    const float* xr = x + rowb + p*24;
    float c[24];
    #pragma unroll
    for (int q = 0; q < 6; q++){
      float4 v = ((const float4*)xr)[q];
      c[q*4+0]=v.x; c[q*4+1]=v.y; c[q*4+2]=v.z; c[q*4+3]=v.w;
    }
    if (p == 0) mw[t] = ndwi[(size_t)b*50176 + sy*224 + sx];
    float s = 0.f, s2 = 0.f;
    #pragma unroll
    for (int j = 0; j < 24; j++){ s += c[j]; s2 += c[j]*c[j]; }
    s  += __shfl_xor(s, 1);  s  += __shfl_xor(s, 2);
    s2 += __shfl_xor(s2, 1); s2 += __shfl_xor(s2, 2);
    float m = s*(1.f/96.f);
    float rs = rsqrtf(s2*(1.f/96.f) - m*m + 1e-5f);
    const int mt = t >> 4, row = t & 15;
    #pragma unroll
    for (int jj = 0; jj < 12; jj++){
      int k = p*24 + 2*jj;
      float a = (c[2*jj]  -m)*rs*n1g[k]   + n1b[k];
      float d = (c[2*jj+1]-m)*rs*n1g[k+1] + n1b[k+1];
      int ks = k >> 5, g = (k & 31) >> 3, i = k & 7;
      *(u32*)&xA[(((mt*3 + ks)*64 + g*16 + row)<<3) + i] = pack2(a, d);
    }
  }
  __syncthreads();

  // QKV via MFMA: wave = m-tile of 16 tokens; B-frags from L2-resident global
  {
    bf16x8 af[3];
    #pragma unroll
    for (int ks = 0; ks < 3; ks++)
      af[ks] = *(const bf16x8*)&xA[((wv_*3 + ks)*64 + ln)*8];
    u16* qpu = (u16*)qp;
    u16* kpu = (u16*)kp;
    const float S = 0.28867513459481287f;
    for (int jt = 0; jt < 18; jt++){
      f32x4 c = (f32x4){0.f,0.f,0.f,0.f};
      #pragma unroll
      for (int ks = 0; ks < 3; ks++){
        bf16x8 bw = *(const bf16x8*)(w8q + ((jt*3 + ks)*64 + ln)*4);
        c = __builtin_amdgcn_mfma_f32_16x16x32_bf16(af[ks], bw, c, 0, 0, 0);
      }
      const int oc = jt*16 + colv;
      const float bv = qb[oc];
      #pragma unroll
      for (int r = 0; r < 4; r++){
        int tok = wv_*16 + rgrp*4 + r;
        if (tok < 49){
          float v = c[r] + bv;
          if (oc < 96)       qpu[tok*98 + oc]        = f2bf(v*S);
          else if (oc < 192) kpu[tok*98 + (oc-96)]   = f2bf(v);
          else               vpT[(oc-192)*50 + tok]  = f2bf(v);
        }
      }
    }
  }
  __syncthreads();

  // attention core (dot2 softmax); output -> xA as A-fragments
  for (int task = tid; task < 392; task += 256){
    int h = task/49, i = task - (task/49)*49;
    int iy = i/7, ix = i - (i/7)*7;
    u32 qv[6];
    #pragma unroll
    for (int e = 0; e < 6; e++) qv[e] = qp[i*49 + h*6 + e];
    const float* rb = &rpb[h*169 + (iy+6)*13 + (ix+6)];
    float s[49]; float mx = -1e30f;
    float mi = mw[i];
    int j = 0;
    #pragma unroll
    for (int jy = 0; jy < 7; jy++)
    #pragma unroll
    for (int jx = 0; jx < 7; jx++, j++){
      const u32* kr = &kp[j*49 + h*6];
      float a = rb[-(jy*13+jx)];
      a = dot2bf(qv[0], kr[0], a); a = dot2bf(qv[1], kr[1], a);
      a = dot2bf(qv[2], kr[2], a); a = dot2bf(qv[3], kr[3], a);
      a = dot2bf(qv[4], kr[4], a); a = dot2bf(qv[5], kr[5], a);
      a = (mi != mw[j]) ? a - 100.f : a;
      s[j] = a; mx = fmaxf(mx, a);
    }
    float l = 0.f;
    #pragma unroll
    for (int jj = 0; jj < 49; jj++){ float p = __expf(s[jj]-mx); s[jj] = p; l += p; }
    float rl = 1.f/l;
    u32 pp[25];
    #pragma unroll
    for (int e = 0; e < 24; e++)
      pp[e] = (__builtin_bit_cast(u32, s[2*e]) >> 16)
            | (__builtin_bit_cast(u32, s[2*e+1]) & 0xffff0000u);
    pp[24] = __builtin_bit_cast(u32, s[48]) >> 16;
    float o[12];
    #pragma unroll
    for (int d = 0; d < 12; d++){
      const u32* vr = (const u32*)(vpT + (h*12+d)*50);
      float od = 0.f;
      #pragma unroll
      for (int e = 0; e < 25; e++) od = dot2bf(pp[e], vr[e], od);
      o[d] = od*rl;
    }
    const int mt2 = i >> 4, row2 = i & 15;
    #pragma unroll
    for (int m = 0; m < 6; m++){
      int k = h*12 + 2*m;
      int ks = k >> 5, g = (k & 31) >> 3, ii = k & 7;
      *(u32*)&xA[(((mt2*3 + ks)*64 + g*16 + row2)<<3) + ii] = pack2(o[2*m], o[2*m+1]);
    }
  }
  __syncthreads();

  // proj via MFMA -> qp (u16, dead after QK^T)
  {
    bf16x8 af[3];
    #pragma unroll
    for (int ks = 0; ks < 3; ks++)
      af[ks] = *(const bf16x8*)&xA[((wv_*3 + ks)*64 + ln)*8];
    u16* qpu = (u16*)qp;
    for (int jt = 0; jt < 6; jt++){
      f32x4 c = (f32x4){0.f,0.f,0.f,0.f};
      #pragma unroll
      for (int ks = 0; ks < 3; ks++){
        bf16x8 bw = *(const bf16x8*)(w8p + ((jt*3 + ks)*64 + ln)*4);
        c = __builtin_amdgcn_mfma_f32_16x16x32_bf16(af[ks], bw, c, 0, 0, 0);
      }
      const int oc = jt*16 + colv;
      const float bv = pb[oc];
      #pragma unroll
      for (int r = 0; r < 4; r++){
        int tok = wv_*16 + rgrp*4 + r;
        if (tok < 49) qpu[tok*98 + oc] = f2bf(c[r] + bv);
      }
    }
  }
  __syncthreads();

  // write: reverse roll (-4) + residual
  for (int e = tid; e < 588; e += 256){
    int t = e/12, g = e - (e/12)*12;
    int ty = t/7, tx = t - (t/7)*7;
    int dy = wy*7 + ty - 4; if (dy < 0) dy += 224;
    int dx = wx*7 + tx - 4; if (dx < 0) dx += 224;
    size_t base = ((size_t)((b*224+dy)*224+dx))*96 + g*8;
    float4 r0 = *(const float4*)(x + base);
    float4 r1 = *(const float4*)(x + base + 4);
    const u32* pr = &qp[t*49 + g*4];
    uint4 ov;
    ov.x = pack2(lo16(pr[0])+r0.x, hi16(pr[0])+r0.y);
    ov.y = pack2(lo16(pr[1])+r0.z, hi16(pr[1])+r0.w);
    ov.z = pack2(lo16(pr[2])+r1.x, hi16(pr[2])+r1.y);
    ov.w = pack2(lo16(pr[3])+r1.z, hi16(pr[3])+r1.w);
    *(uint4*)(x1o + base) = ov;
  }
}

// ---------------------------------------------------------------------------
// K2a: MLP, B-fragments direct from global (R16-verified).
// ---------------------------------------------------------------------------
__global__ __launch_bounds__(256,4) void mlp_direct_k(
    const u16* __restrict__ x1, const u32* __restrict__ wm,
    const float* __restrict__ b1, const float* __restrict__ b2,
    const float* __restrict__ g2, const float* __restrict__ bb2,
    float* __restrict__ x2o)
{
  __shared__ __align__(16) u16 xA[4*3*64*8];
  __shared__ __align__(16) u16 hA[4*3*64*8];
  const int tid = threadIdx.x;
  const size_t t0 = (size_t)blockIdx.x * 64;
  const int wvM = tid >> 6;
  const int ln  = tid & 63;
  const int colv = ln & 15, rgrp = ln >> 4;
  const u32* w1m = wm;
  const u32* w2m = wm + 18432;

  {
    const int t = tid >> 2, p = tid & 3;
    const u16* xr = x1 + (t0 + t)*96 + p*24;
    float c[24];
    #pragma unroll
    for (int q = 0; q < 3; q++){
      uint4 v = ((const uint4*)xr)[q];
      c[q*8+0]=lo16(v.x); c[q*8+1]=hi16(v.x);
      c[q*8+2]=lo16(v.y); c[q*8+3]=hi16(v.y);
      c[q*8+4]=lo16(v.z); c[q*8+5]=hi16(v.z);
      c[q*8+6]=lo16(v.w); c[q*8+7]=hi16(v.w);
    }
    float s = 0.f, s2 = 0.f;
    #pragma unroll
    for (int j = 0; j < 24; j++){ s += c[j]; s2 += c[j]*c[j]; }
    s  += __shfl_xor(s, 1);  s  += __shfl_xor(s, 2);
    s2 += __shfl_xor(s2, 1); s2 += __shfl_xor(s2, 2);
    float m = s*(1.f/96.f);
    float rs = rsqrtf(s2*(1.f/96.f) - m*m + 1e-5f);
    const int mt = t >> 4, row = t & 15;
    #pragma unroll
    for (int jj = 0; jj < 12; jj++){
      int k = p*24 + 2*jj;
      float a = (c[2*jj]  -m)*rs*g2[k]   + bb2[k];
      float d = (c[2*jj+1]-m)*rs*g2[k+1] + bb2[k+1];
      int ks = k >> 5, g = (k & 31) >> 3, i = k & 7;
      *(u32*)&xA[(((mt*3 + ks)*64 + g*16 + row)<<3) + i] = pack2(a, d);
    }
  }
  __syncthreads();

  bf16x8 af[3];
  #pragma unroll
  for (int ks = 0; ks < 3; ks++)
    af[ks] = *(const bf16x8*)&xA[((wvM*3 + ks)*64 + ln)*8];

  f32x4 acc2[6];
  #pragma unroll
  for (int j = 0; j < 6; j++) acc2[j] = (f32x4){0.f,0.f,0.f,0.f};

  for (int q = 0; q < 4; q++){
    __syncthreads();
    #pragma unroll
    for (int j = 0; j < 6; j++){
      f32x4 c = (f32x4){0.f,0.f,0.f,0.f};
      #pragma unroll
      for (int ks = 0; ks < 3; ks++){
        bf16x8 bfv = *(const bf16x8*)(w1m + ((q*18 + j*3 + ks)*64 + ln)*4);
        c = __builtin_amdgcn_mfma_f32_16x16x32_bf16(af[ks], bfv, c, 0, 0, 0);
      }
      const float bv = b1[q*96 + j*16 + colv];
      const int kq = j*16 + colv;
      const int ks2 = kq >> 5, gg = (kq & 31) >> 3, ii = kq & 7;
      u16* hdst = &hA[(((wvM*3 + ks2)*64 + gg*16)<<3) + ii];
      #pragma unroll
      for (int r = 0; r < 4; r++){
        int rowh = rgrp*4 + r;
        hdst[rowh*8] = f2bf(gelu(c[r] + bv));
      }
    }
    __syncthreads();

    bf16x8 hf[3];
    #pragma unroll
    for (int ks = 0; ks < 3; ks++)
      hf[ks] = *(const bf16x8*)&hA[((wvM*3 + ks)*64 + ln)*8];
    #pragma unroll
    for (int j = 0; j < 6; j++){
      #pragma unroll
      for (int ks = 0; ks < 3; ks++){
        bf16x8 bfv = *(const bf16x8*)(w2m + ((q*18 + j*3 + ks)*64 + ln)*4);
        acc2[j] = __builtin_amdgcn_mfma_f32_16x16x32_bf16(hf[ks], bfv, acc2[j], 0, 0, 0);
      }
    }
  }

  #pragma unroll
  for (int j = 0; j < 6; j++){
    const int oc = j*16 + colv;
    const float bv = b2[oc];
    #pragma unroll
    for (int r = 0; r < 4; r++){
      size_t tok = t0 + wvM*16 + rgrp*4 + r;
      x2o[tok*96 + oc] = acc2[j][r] + bv + bf2f(x1[tok*96 + oc]);
    }
  }
}

// ---------------------------------------------------------------------------
// K2b: MLP, staged fallback (R15-verified).
// ---------------------------------------------------------------------------
__global__ __launch_bounds__(256,2) void mlp_stage_k(
    const u16* __restrict__ x1, const float* __restrict__ w1, const float* __restrict__ b1,
    const float* __restrict__ w2, const float* __restrict__ b2,
    const float* __restrict__ g2, const float* __restrict__ bb2,
    float* __restrict__ x2o)
{
  __shared__ __align__(16) u16 xA [4*3*64*8];
  __shared__ __align__(16) u16 hA [4*3*64*8];
  __shared__ __align__(16) u16 w1f[6*3*64*8];
  __shared__ __align__(16) u16 w2f[6*3*64*8];
  const int tid = threadIdx.x;
  const size_t t0 = (size_t)blockIdx.x * 64;
  const int wvM = tid >> 6;
  const int ln  = tid & 63;
  const int colv = ln & 15, rgrp = ln >> 4;

  {
    const int t = tid >> 2, p = tid & 3;
    const u16* xr = x1 + (t0 + t)*96 + p*24;
    float c[24];
    #pragma unroll
    for (int q = 0; q < 3; q++){
      uint4 v = ((const uint4*)xr)[q];
      c[q*8+0]=lo16(v.x); c[q*8+1]=hi16(v.x);
      c[q*8+2]=lo16(v.y); c[q*8+3]=hi16(v.y);
      c[q*8+4]=lo16(v.z); c[q*8+5]=hi16(v.z);
      c[q*8+6]=lo16(v.w); c[q*8+7]=hi16(v.w);
    }
    float s = 0.f, s2 = 0.f;
    #pragma unroll
    for (int j = 0; j < 24; j++){ s += c[j]; s2 += c[j]*c[j]; }
    s  += __shfl_xor(s, 1);  s  += __shfl_xor(s, 2);
    s2 += __shfl_xor(s2, 1); s2 += __shfl_xor(s2, 2);
    float m = s*(1.f/96.f);
    float rs = rsqrtf(s2*(1.f/96.f) - m*m + 1e-5f);
    const int mt = t >> 4, row = t & 15;
    #pragma unroll
    for (int jj = 0; jj < 12; jj++){
      int k = p*24 + 2*jj;
      float a = (c[2*jj]  -m)*rs*g2[k]   + bb2[k];
      float d = (c[2*jj+1]-m)*rs*g2[k+1] + bb2[k+1];
      int ks = k >> 5, g = (k & 31) >> 3, i = k & 7;
      *(u32*)&xA[(((mt*3 + ks)*64 + g*16 + row)<<3) + i] = pack2(a, d);
    }
  }

  f32x4 acc2[6];
  #pragma unroll
  for (int j = 0; j < 6; j++) acc2[j] = (f32x4){0.f,0.f,0.f,0.f};

  for (int q = 0; q < 4; q++){
    __syncthreads();
    for (int e = tid; e < 4608; e += 256){
      int n = e/48, cp = e - (e/48)*48, k = cp*2;
      int ks = k >> 5, g = (k & 31) >> 3, i = k & 7;
      int fidx = ((((n>>4)*3 + ks)*64 + g*16 + (n&15))<<3) + i;
      {
        const float* s = w1 + (size_t)(q*96 + n)*96 + k;
        *(u32*)&w1f[fidx] = pack2(s[0], s[1]);
      }
      {
        const float* s = w2 + (size_t)n*384 + q*96 + k;
        *(u32*)&w2f[fidx] = pack2(s[0], s[1]);
      }
    }
    __syncthreads();

    bf16x8 af[3];
    #pragma unroll
    for (int ks = 0; ks < 3; ks++)
      af[ks] = *(const bf16x8*)&xA[((wvM*3 + ks)*64 + ln)*8];
    #pragma unroll
    for (int j = 0; j < 6; j++){
      f32x4 c = (f32x4){0.f,0.f,0.f,0.f};
      #pragma unroll
      for (int ks = 0; ks < 3; ks++){
        bf16x8 bfv = *(const bf16x8*)&w1f[((j*3 + ks)*64 + ln)*8];
        c = __builtin_amdgcn_mfma_f32_16x16x32_bf16(af[ks], bfv, c, 0, 0, 0);
      }
      const float bv = b1[q*96 + j*16 + colv];
      const int kq = j*16 + colv;
      const int ks2 = kq >> 5, gg = (kq & 31) >> 3, ii = kq & 7;
      u16* hdst = &hA[(((wvM*3 + ks2)*64 + gg*16)<<3) + ii];
      #pragma unroll
      for (int r = 0; r < 4; r++){
        int rowh = rgrp*4 + r;
        hdst[rowh*8] = f2bf(gelu(c[r] + bv));
      }
    }
    __syncthreads();

    bf16x8 hf[3];
    #pragma unroll
    for (int ks = 0; ks < 3; ks++)
      hf[ks] = *(const bf16x8*)&hA[((wvM*3 + ks)*64 + ln)*8];
    #pragma unroll
    for (int j = 0; j < 6; j++){
      #pragma unroll
      for (int ks = 0; ks < 3; ks++){
        bf16x8 bfv = *(const bf16x8*)&w2f[((j*3 + ks)*64 + ln)*8];
        acc2[j] = __builtin_amdgcn_mfma_f32_16x16x32_bf16(hf[ks], bfv, acc2[j], 0, 0, 0);
      }
    }
  }

  #pragma unroll
  for (int j = 0; j < 6; j++){
    const int oc = j*16 + colv;
    const float bv = b2[oc];
    #pragma unroll
    for (int r = 0; r < 4; r++){
      size_t tok = t0 + wvM*16 + rgrp*4 + r;
      x2o[tok*96 + oc] = acc2[j][r] + bv + bf2f(x1[tok*96 + oc]);
    }
  }
}

// ---------------------------------------------------------------------------
// K3: MFMA implicit-GEMM 3x3 conv (R16-verified).
// ---------------------------------------------------------------------------
template<int DIL, bool LN3, bool FINAL, bool WD>
__global__ __launch_bounds__(256,4) void convm_k(
    const void* __restrict__ srcv, const u32* __restrict__ wpk,
    const float* __restrict__ wOIHW,
    const float* __restrict__ cb, const float* __restrict__ bng, const float* __restrict__ bnb,
    const float* __restrict__ bnm, const float* __restrict__ bnv,
    const float* __restrict__ g3, const float* __restrict__ b3,
    const float* resid, void* dstv)
{
  constexpr int SY = 8 + 2*DIL, SX = 8 + 2*DIL, NPIX = SY*SX;
  __shared__ __align__(16) u16 inT[NPIX*104];
  const int tid = threadIdx.x;
  const int bx = blockIdx.x*8, by = blockIdx.y*8, b = blockIdx.z;
  const int gy0 = by - DIL, gx0 = bx - DIL;

  for (int e = tid; e < NPIX*48; e += 256){
    int p = e/48, c2 = e - (e/48)*48;
    int y = p/SX, xx = p - (p/SX)*SX;
    int gy = gy0+y, gx = gx0+xx;
    u32 v = 0;
    if (gy >= 0 && gy < 224 && gx >= 0 && gx < 224){
      size_t idx = ((size_t)((b*224+gy)*224+gx))*96 + c2*2;
      if (LN3){
        float2 rd = *(const float2*)((const float*)srcv + idx);
        v = pack2(rd.x, rd.y);
      } else {
        v = *(const u32*)((const u16*)srcv + idx);
      }
    }
    *(u32*)&inT[p*104 + c2*2] = v;
  }
  __syncthreads();
  if (LN3){
    if (tid < 2*NPIX){
      const int p = tid >> 1, half = tid & 1;
      int y = p/SX, xx = p - (p/SX)*SX;
      int gy = gy0+y, gx = gx0+xx;
      if (gy >= 0 && gy < 224 && gx >= 0 && gx < 224){
        u32* row = (u32*)&inT[p*104] + half*24;
        float c[48];
        #pragma unroll
        for (int i = 0; i < 24; i++){ u32 v = row[i]; c[2*i] = lo16(v); c[2*i+1] = hi16(v); }
        float s = 0.f, s2 = 0.f;
        #pragma unroll
        for (int i = 0; i < 48; i++){ s += c[i]; s2 += c[i]*c[i]; }
        s  += __shfl_xor(s, 1);
        s2 += __shfl_xor(s2, 1);
        float m = s*(1.f/96.f);
        float rs = rsqrtf(s2*(1.f/96.f) - m*m + 1e-5f);
        const int cbase = half*48;
        #pragma unroll
        for (int i = 0; i < 24; i++){
          float a = (c[2*i]  -m)*rs*g3[cbase+2*i]   + b3[cbase+2*i];
          float d = (c[2*i+1]-m)*rs*g3[cbase+2*i+1] + b3[cbase+2*i+1];
          row[i] = pack2(a, d);
        }
      }
    }
    __syncthreads();
  }

  const int wvM = tid >> 6, ln = tid & 63;
  const int colv = ln & 15, rgrp = ln >> 4;
  const int arow = ln & 15;
  const int aoy = wvM*2 + (arow >> 3), aox = arow & 7;

  f32x4 acc[6];
  #pragma unroll
  for (int j = 0; j < 6; j++) acc[j] = (f32x4){0.f,0.f,0.f,0.f};

  if constexpr (WD){
    #pragma unroll 3
    for (int tap = 0; tap < 9; tap++){
      const int ky = tap/3, kx = tap - (tap/3)*3;
      const int p_in = (aoy + ky*DIL)*SX + aox + kx*DIL;
      bf16x8 af[3];
      #pragma unroll
      for (int ks = 0; ks < 3; ks++)
        af[ks] = *(const bf16x8*)&inT[p_in*104 + ks*32 + rgrp*8];
      const u32* wt = wpk + tap*4608;
      #pragma unroll
      for (int j = 0; j < 6; j++){
        #pragma unroll
        for (int ks = 0; ks < 3; ks++){
          bf16x8 bfv = *(const bf16x8*)(wt + ((j*3 + ks)*64 + ln)*4);
          acc[j] = __builtin_amdgcn_mfma_f32_16x16x32_bf16(af[ks], bfv, acc[j], 0, 0, 0);
        }
      }
    }
  } else {
    __shared__ __align__(16) u32 wfr[4608];
    for (int tap = 0; tap < 9; tap++){
      const int ky = tap/3, kx = tap - (tap/3)*3;
      __syncthreads();
      for (int e = tid; e < 4608; e += 256){
        int jk = e >> 8, lane = (e >> 2) & 63, q = e & 3;
        int j = jk/3, ks = jk - j*3;
        int n = j*16 + (lane & 15);
        int k = ks*32 + (lane >> 4)*8 + 2*q;
        wfr[e] = pack2(wOIHW[(n*96 + k)*9 + tap], wOIHW[(n*96 + k + 1)*9 + tap]);
      }
      __syncthreads();
      const int p_in = (aoy + ky*DIL)*SX + aox + kx*DIL;
      bf16x8 af[3];
      #pragma unroll
      for (int ks = 0; ks < 3; ks++)
        af[ks] = *(const bf16x8*)&inT[p_in*104 + ks*32 + rgrp*8];
      #pragma unroll
      for (int j = 0; j < 6; j++){
        #pragma unroll
        for (int ks = 0; ks < 3; ks++){
          bf16x8 bfv = *(const bf16x8*)((const u16*)wfr + ((j*3 + ks)*64 + ln)*8);
          acc[j] = __builtin_amdgcn_mfma_f32_16x16x32_bf16(af[ks], bfv, acc[j], 0, 0, 0);
        }
      }
    }
  }

  #pragma unroll
  for (int j = 0; j < 6; j++){
    const int oc = j*16 + colv;
    const float sc = bng[oc]*rsqrtf(bnv[oc]+1e-5f);
    const float mm = bnm[oc], bb = bnb[oc], cbv = cb[oc];
    #pragma unroll
    for (int r = 0; r < 4; r++){
      const int rowm = rgrp*4 + r;
      const int gy = by + wvM*2 + (rowm >> 3), gx = bx + (rowm & 7);
      size_t idx = ((size_t)((b*224+gy)*224+gx))*96 + oc;
      float t = (acc[j][r] + cbv - mm)*sc + bb;
      float o = gelu(t);
      if (FINAL){
        ((float*)dstv)[idx] = o + resid[idx];
      } else {
        ((u16*)dstv)[idx] = f2bf(o);
      }
    }
  }
}

// ---------------------------------------------------------------------------
extern "C" void kernel_launch(void* const* d_in, const int* in_sizes, int n_in,
                              void* d_out, int out_size, void* d_ws, size_t ws_size,
                              hipStream_t stream)
{
  const float* x    = (const float*)d_in[0];
  const float* ndwi = (const float*)d_in[1];
  const float* n1g  = (const float*)d_in[2];
  const float* n1b  = (const float*)d_in[3];
  const float* qkvw = (const float*)d_in[4];
  const float* qkvb = (const float*)d_in[5];
  const float* projw= (const float*)d_in[6];
  const float* projb= (const float*)d_in[7];
  const float* rpbt = (const float*)d_in[8];
  const float* n2g  = (const float*)d_in[9];
  const float* n2b  = (const float*)d_in[10];
  const float* w1   = (const float*)d_in[11];
  const float* b1   = (const float*)d_in[12];
  const float* w2   = (const float*)d_in[13];
  const float* b2   = (const float*)d_in[14];
  const float* n3g  = (const float*)d_in[15];
  const float* n3b  = (const float*)d_in[16];
  const float* c1w  = (const float*)d_in[17];
  const float* c1b  = (const float*)d_in[18];
  const float* bn1g = (const float*)d_in[19];
  const float* bn1b = (const float*)d_in[20];
  const float* bn1m = (const float*)d_in[21];
  const float* bn1v = (const float*)d_in[22];
  const float* c2w  = (const float*)d_in[23];
  const float* c2b  = (const float*)d_in[24];
  const float* bn2g = (const float*)d_in[25];
  const float* bn2b = (const float*)d_in[26];
  const float* bn2m = (const float*)d_in[27];
  const float* bn2v = (const float*)d_in[28];

  int B = out_size / (224*224*96);
  if (B < 1 || B > 64) B = 4;
  const size_t elems = (size_t)B*224*224*96;

  u16*   wsA = (u16*)d_ws;
  u32*   w8q = (u32*)d_out;
  u32*   w8p = w8q + 13824;
  float* xo  = (float*)d_out;
  u32*   wcv = nullptr;
  u32*   wm  = nullptr;
  if (ws_size >= elems*sizeof(u16) + 82944*sizeof(u32))
    wcv = (u32*)(wsA + elems);
  if (ws_size >= elems*sizeof(u16) + (82944 + 36864)*sizeof(u32))
    wm = wcv + 82944;

  wprep_k<<<dim3(72), dim3(256), 0, stream>>>(qkvw, projw, w8q, w8p);
  if (wcv) wprep_cv<<<dim3(324), dim3(256), 0, stream>>>(c1w, c2w, wcv);
  if (wm)  wprep_m<<<dim3(144), dim3(256), 0, stream>>>(w1, w2, wm);
  attn_k<<<dim3(B*1024), dim3(256), 0, stream>>>(x, ndwi, n1g, n1b, w8q, qkvb, w8p, projb, rpbt, wsA);
  if (wm)
    mlp_direct_k<<<dim3(B*784), dim3(256), 0, stream>>>(wsA, wm, b1, b2, n2g, n2b, xo);
  else
    mlp_stage_k<<<dim3(B*784), dim3(256), 0, stream>>>(wsA, w1, b1, w2, b2, n2g, n2b, xo);
  if (wcv){
    convm_k<1,true ,false,true ><<<dim3(28,28,B), dim3(256), 0, stream>>>(
        xo,  wcv,        c1w, c1b, bn1g, bn1b, bn1m, bn1v, n3g, n3b, nullptr, wsA);
    convm_k<2,false,true ,true ><<<dim3(28,28,B), dim3(256), 0, stream>>>(
        wsA, wcv+41472,  c2w, c2b, bn2g, bn2b, bn2m, bn2v, nullptr, nullptr, xo, xo);
  } else {
    convm_k<1,true ,false,false><<<dim3(28,28,B), dim3(256), 0, stream>>>(
        xo,  nullptr,    c1w, c1b, bn1g, bn1b, bn1m, bn1v, n3g, n3b, nullptr, wsA);
    convm_k<2,false,true ,false><<<dim3(28,28,B), dim3(256), 0, stream>>>(
        wsA, nullptr,    c2w, c2b, bn2g, bn2b, bn2m, bn2v, nullptr, nullptr, xo, xo);
  }
}

// Round 20
// 494.631 us; speedup vs baseline: 1.1964x; 1.1229x over previous
//
#include <hip/hip_runtime.h>
#include <hip/hip_bf16.h>

typedef unsigned int u32;
typedef unsigned short u16;

#define DF __device__ __forceinline__

DF float bf2f(u16 v){ u32 t = ((u32)v)<<16; return __builtin_bit_cast(float, t); }
DF u16 f2bf(float f){
  u32 t = __builtin_bit_cast(u32, f);
  t += 0x7fffu + ((t>>16)&1u);
  return (u16)(t>>16);
}
DF float lo16(u32 p){ return __builtin_bit_cast(float, p<<16); }
DF float hi16(u32 p){ return __builtin_bit_cast(float, p & 0xffff0000u); }
DF u32 pack2(float a, float b){ return (u32)f2bf(a) | (((u32)f2bf(b))<<16); }
DF float gelu(float x){ return 0.5f*x*(1.0f+erff(x*0.70710678118654752f)); }

#if defined(__has_builtin)
#if __has_builtin(__builtin_amdgcn_fdot2_f32_bf16)
#define HAVE_DOT2 1
#endif
#endif
#ifdef HAVE_DOT2
DF float dot2bf(u32 a, u32 b, float c){
  typedef __bf16 b2 __attribute__((ext_vector_type(2)));
  return __builtin_amdgcn_fdot2_f32_bf16(__builtin_bit_cast(b2,a), __builtin_bit_cast(b2,b), c, false);
}
#else
DF float dot2bf(u32 a, u32 b, float c){
  float d;
  asm("v_dot2_f32_bf16 %0, %1, %2, %3" : "=v"(d) : "v"(a), "v"(b), "v"(c));
  return d;
}
#endif

typedef __attribute__((ext_vector_type(8))) __bf16 bf16x8;
typedef __attribute__((ext_vector_type(4))) float f32x4;

// ---------------------------------------------------------------------------
// K0: pack qkv/proj weights as MFMA B-fragments (front of d_out).
// ---------------------------------------------------------------------------
__global__ void wprep_k(const float* __restrict__ qkvw, const float* __restrict__ projw,
                        u32* __restrict__ w8q, u32* __restrict__ w8p)
{
  int e = blockIdx.x*256 + threadIdx.x;
  if (e < 13824){
    int jk = e >> 8, lane = (e >> 2) & 63, q = e & 3;
    int jt = jk/3, ks = jk - jt*3;
    int n = jt*16 + (lane & 15);
    int k = ks*32 + (lane >> 4)*8 + 2*q;
    w8q[e] = pack2(qkvw[n*96 + k], qkvw[n*96 + k + 1]);
  } else if (e < 18432){
    int r2 = e - 13824;
    int jk = r2 >> 8, lane = (r2 >> 2) & 63, q = r2 & 3;
    int jt = jk/3, ks = jk - jt*3;
    int n = jt*16 + (lane & 15);
    int k = ks*32 + (lane >> 4)*8 + 2*q;
    w8p[r2] = pack2(projw[n*96 + k], projw[n*96 + k + 1]);
  }
}

// ---------------------------------------------------------------------------
// K0b: conv weights as MFMA B-fragments into ws tail.
// ---------------------------------------------------------------------------
__global__ void wprep_cv(const float* __restrict__ c1w, const float* __restrict__ c2w,
                         u32* __restrict__ wcv)
{
  int e = blockIdx.x*256 + threadIdx.x;
  if (e >= 82944) return;
  int conv = e / 41472, r = e - conv*41472;
  int tap = r / 4608, r2 = r - tap*4608;
  int jk = r2 >> 8;
  int lane = (r2 >> 2) & 63;
  int q = r2 & 3;
  int j = jk/3, ks = jk - j*3;
  int n = j*16 + (lane & 15);
  int k = ks*32 + (lane >> 4)*8 + 2*q;
  const float* s = conv ? c2w : c1w;
  wcv[e] = pack2(s[(n*96 + k)*9 + tap], s[(n*96 + k + 1)*9 + tap]);
}

// ---------------------------------------------------------------------------
// K0c: mlp w1/w2 as MFMA B-fragments into ws tail (after wcv).
// ---------------------------------------------------------------------------
__global__ void wprep_m(const float* __restrict__ w1, const float* __restrict__ w2,
                        u32* __restrict__ wm)
{
  int e = blockIdx.x*256 + threadIdx.x;
  if (e >= 36864) return;
  int which = e / 18432, r = e - which*18432;
  int q = r / 4608, r2 = r - q*4608;
  int jk = r2 >> 8, lane = (r2 >> 2) & 63, qq = r2 & 3;
  int jt = jk/3, ks = jk - jt*3;
  int n = jt*16 + (lane & 15);
  int k = ks*32 + (lane >> 4)*8 + 2*qq;
  if (which == 0){
    const float* s = w1 + (size_t)(q*96 + n)*96 + k;
    wm[e] = pack2(s[0], s[1]);
  } else {
    const float* s = w2 + (size_t)n*384 + q*96 + k;
    wm[e] = pack2(s[0], s[1]);
  }
}

// ---------------------------------------------------------------------------
// K1: fused windowed attention — 512-thread edition.
// 8 waves: QKV jt-range split across wave-halves (18 -> 9 per wave), softmax
// core single-round (392 tasks <= 512 threads), proj 6 -> 3 jt per wave.
// Same LDS (47KB) -> 3 blocks/CU. Math identical to R16 (232us verified).
// ---------------------------------------------------------------------------
__global__ __launch_bounds__(512,4) void attn_k(
    const float* __restrict__ x, const float* __restrict__ ndwi,
    const float* __restrict__ n1g, const float* __restrict__ n1b,
    const u32* __restrict__ w8q, const float* __restrict__ qb,
    const u32* __restrict__ w8p, const float* __restrict__ pb,
    const float* __restrict__ rpbt, u16* __restrict__ x1o)
{
  __shared__ __align__(16) u16 xA[4*3*64*8];  // x A-frags; later attn-out A-frags
  __shared__ u32 qp[49*49];    // q as u16[49][98]; later proj-out
  __shared__ u32 kp[49*49];    // k as u16[49][98]
  __shared__ u16 vpT[96*50];   // v transposed [d][j]
  __shared__ float rpb[8*169];
  __shared__ float mw[49];
  const int tid = threadIdx.x;
  const int blk = blockIdx.x;
  const int b = blk >> 10, wy = (blk>>5)&31, wx = blk&31;
  const int wv_ = __builtin_amdgcn_readfirstlane(tid >> 6);   // 0..7
  const int ln  = tid & 63;
  const int colv = ln & 15, rgrp = ln >> 4;

  for (int i = tid; i < 1352; i += 512){
    int h = i/169, idx = i - h*169;
    rpb[i] = rpbt[idx*8 + h];
  }
  for (int i = tid; i < 96; i += 512) vpT[i*50 + 49] = 0;

  // LN1 straight from global -> xA fragments (4 lanes per token)
  if (tid < 196){
    const int t = tid >> 2, p = tid & 3;
    const int ty = t/7, tx = t - (t/7)*7;
    int sy = wy*7 + ty - 3; if (sy < 0) sy += 224;
    int sx = wx*7 + tx - 3; if (sx < 0) sx += 224;
    const size_t rowb = ((size_t)((b*224 + sy)*224 + sx))*96;
    const float* xr = x + rowb + p*24;
    float c[24];
    #pragma unroll
    for (int q = 0; q < 6; q++){
      float4 v = ((const float4*)xr)[q];
      c[q*4+0]=v.x; c[q*4+1]=v.y; c[q*4+2]=v.z; c[q*4+3]=v.w;
    }
    if (p == 0) mw[t] = ndwi[(size_t)b*50176 + sy*224 + sx];
    float s = 0.f, s2 = 0.f;
    #pragma unroll
    for (int j = 0; j < 24; j++){ s += c[j]; s2 += c[j]*c[j]; }
    s  += __shfl_xor(s, 1);  s  += __shfl_xor(s, 2);
    s2 += __shfl_xor(s2, 1); s2 += __shfl_xor(s2, 2);
    float m = s*(1.f/96.f);
    float rs = rsqrtf(s2*(1.f/96.f) - m*m + 1e-5f);
    const int mt = t >> 4, row = t & 15;
    #pragma unroll
    for (int jj = 0; jj < 12; jj++){
      int k = p*24 + 2*jj;
      float a = (c[2*jj]  -m)*rs*n1g[k]   + n1b[k];
      float d = (c[2*jj+1]-m)*rs*n1g[k+1] + n1b[k+1];
      int ks = k >> 5, g = (k & 31) >> 3, i = k & 7;
      *(u32*)&xA[(((mt*3 + ks)*64 + g*16 + row)<<3) + i] = pack2(a, d);
    }
  }
  __syncthreads();

  // QKV via MFMA: wave = (m-tile = wv_&3, jt-half = wv_>>2)
  {
    const int mtile = wv_ & 3;
    const int jt0 = (wv_ >> 2) * 9;
    bf16x8 af[3];
    #pragma unroll
    for (int ks = 0; ks < 3; ks++)
      af[ks] = *(const bf16x8*)&xA[((mtile*3 + ks)*64 + ln)*8];
    u16* qpu = (u16*)qp;
    u16* kpu = (u16*)kp;
    const float S = 0.28867513459481287f;
    for (int jti = 0; jti < 9; jti++){
      const int jt = jt0 + jti;
      f32x4 c = (f32x4){0.f,0.f,0.f,0.f};
      #pragma unroll
      for (int ks = 0; ks < 3; ks++){
        bf16x8 bw = *(const bf16x8*)(w8q + ((jt*3 + ks)*64 + ln)*4);
        c = __builtin_amdgcn_mfma_f32_16x16x32_bf16(af[ks], bw, c, 0, 0, 0);
      }
      const int oc = jt*16 + colv;
      const float bv = qb[oc];
      #pragma unroll
      for (int r = 0; r < 4; r++){
        int tok = mtile*16 + rgrp*4 + r;
        if (tok < 49){
          float v = c[r] + bv;
          if (oc < 96)       qpu[tok*98 + oc]        = f2bf(v*S);
          else if (oc < 192) kpu[tok*98 + (oc-96)]   = f2bf(v);
          else               vpT[(oc-192)*50 + tok]  = f2bf(v);
        }
      }
    }
  }
  __syncthreads();

  // attention core (dot2 softmax), single round; output -> xA A-fragments
  if (tid < 392){
    const int task = tid;
    int h = task/49, i = task - (task/49)*49;
    int iy = i/7, ix = i - (i/7)*7;
    u32 qv[6];
    #pragma unroll
    for (int e = 0; e < 6; e++) qv[e] = qp[i*49 + h*6 + e];
    const float* rb = &rpb[h*169 + (iy+6)*13 + (ix+6)];
    float s[49]; float mx = -1e30f;
    float mi = mw[i];
    int j = 0;
    #pragma unroll
    for (int jy = 0; jy < 7; jy++)
    #pragma unroll
    for (int jx = 0; jx < 7; jx++, j++){
      const u32* kr = &kp[j*49 + h*6];
      float a = rb[-(jy*13+jx)];
      a = dot2bf(qv[0], kr[0], a); a = dot2bf(qv[1], kr[1], a);
      a = dot2bf(qv[2], kr[2], a); a = dot2bf(qv[3], kr[3], a);
      a = dot2bf(qv[4], kr[4], a); a = dot2bf(qv[5], kr[5], a);
      a = (mi != mw[j]) ? a - 100.f : a;
      s[j] = a; mx = fmaxf(mx, a);
    }
    float l = 0.f;
    #pragma unroll
    for (int jj = 0; jj < 49; jj++){ float p = __expf(s[jj]-mx); s[jj] = p; l += p; }
    float rl = 1.f/l;
    u32 pp[25];
    #pragma unroll
    for (int e = 0; e < 24; e++)
      pp[e] = (__builtin_bit_cast(u32, s[2*e]) >> 16)
            | (__builtin_bit_cast(u32, s[2*e+1]) & 0xffff0000u);
    pp[24] = __builtin_bit_cast(u32, s[48]) >> 16;
    float o[12];
    #pragma unroll
    for (int d = 0; d < 12; d++){
      const u32* vr = (const u32*)(vpT + (h*12+d)*50);
      float od = 0.f;
      #pragma unroll
      for (int e = 0; e < 25; e++) od = dot2bf(pp[e], vr[e], od);
      o[d] = od*rl;
    }
    const int mt2 = i >> 4, row2 = i & 15;
    #pragma unroll
    for (int m = 0; m < 6; m++){
      int k = h*12 + 2*m;
      int ks = k >> 5, g = (k & 31) >> 3, ii = k & 7;
      *(u32*)&xA[(((mt2*3 + ks)*64 + g*16 + row2)<<3) + ii] = pack2(o[2*m], o[2*m+1]);
    }
  }
  __syncthreads();

  // proj via MFMA -> qp (u16, dead after QK^T); jt split across wave halves
  {
    const int mtile = wv_ & 3;
    const int jt0 = (wv_ >> 2) * 3;
    bf16x8 af[3];
    #pragma unroll
    for (int ks = 0; ks < 3; ks++)
      af[ks] = *(const bf16x8*)&xA[((mtile*3 + ks)*64 + ln)*8];
    u16* qpu = (u16*)qp;
    for (int jti = 0; jti < 3; jti++){
      const int jt = jt0 + jti;
      f32x4 c = (f32x4){0.f,0.f,0.f,0.f};
      #pragma unroll
      for (int ks = 0; ks < 3; ks++){
        bf16x8 bw = *(const bf16x8*)(w8p + ((jt*3 + ks)*64 + ln)*4);
        c = __builtin_amdgcn_mfma_f32_16x16x32_bf16(af[ks], bw, c, 0, 0, 0);
      }
      const int oc = jt*16 + colv;
      const float bv = pb[oc];
      #pragma unroll
      for (int r = 0; r < 4; r++){
        int tok = mtile*16 + rgrp*4 + r;
        if (tok < 49) qpu[tok*98 + oc] = f2bf(c[r] + bv);
      }
    }
  }
  __syncthreads();

  // write: reverse roll (-4) + residual
  for (int e = tid; e < 588; e += 512){
    int t = e/12, g = e - (e/12)*12;
    int ty = t/7, tx = t - (t/7)*7;
    int dy = wy*7 + ty - 4; if (dy < 0) dy += 224;
    int dx = wx*7 + tx - 4; if (dx < 0) dx += 224;
    size_t base = ((size_t)((b*224+dy)*224+dx))*96 + g*8;
    float4 r0 = *(const float4*)(x + base);
    float4 r1 = *(const float4*)(x + base + 4);
    const u32* pr = &qp[t*49 + g*4];
    uint4 ov;
    ov.x = pack2(lo16(pr[0])+r0.x, hi16(pr[0])+r0.y);
    ov.y = pack2(lo16(pr[1])+r0.z, hi16(pr[1])+r0.w);
    ov.z = pack2(lo16(pr[2])+r1.x, hi16(pr[2])+r1.y);
    ov.w = pack2(lo16(pr[3])+r1.z, hi16(pr[3])+r1.w);
    *(uint4*)(x1o + base) = ov;
  }
}

// ---------------------------------------------------------------------------
// K2a: MLP, B-fragments direct from global (R16-verified).
// ---------------------------------------------------------------------------
__global__ __launch_bounds__(256,4) void mlp_direct_k(
    const u16* __restrict__ x1, const u32* __restrict__ wm,
    const float* __restrict__ b1, const float* __restrict__ b2,
    const float* __restrict__ g2, const float* __restrict__ bb2,
    float* __restrict__ x2o)
{
  __shared__ __align__(16) u16 xA[4*3*64*8];
  __shared__ __align__(16) u16 hA[4*3*64*8];
  const int tid = threadIdx.x;
  const size_t t0 = (size_t)blockIdx.x * 64;
  const int wvM = tid >> 6;
  const int ln  = tid & 63;
  const int colv = ln & 15, rgrp = ln >> 4;
  const u32* w1m = wm;
  const u32* w2m = wm + 18432;

  {
    const int t = tid >> 2, p = tid & 3;
    const u16* xr = x1 + (t0 + t)*96 + p*24;
    float c[24];
    #pragma unroll
    for (int q = 0; q < 3; q++){
      uint4 v = ((const uint4*)xr)[q];
      c[q*8+0]=lo16(v.x); c[q*8+1]=hi16(v.x);
      c[q*8+2]=lo16(v.y); c[q*8+3]=hi16(v.y);
      c[q*8+4]=lo16(v.z); c[q*8+5]=hi16(v.z);
      c[q*8+6]=lo16(v.w); c[q*8+7]=hi16(v.w);
    }
    float s = 0.f, s2 = 0.f;
    #pragma unroll
    for (int j = 0; j < 24; j++){ s += c[j]; s2 += c[j]*c[j]; }
    s  += __shfl_xor(s, 1);  s  += __shfl_xor(s, 2);
    s2 += __shfl_xor(s2, 1); s2 += __shfl_xor(s2, 2);
    float m = s*(1.f/96.f);
    float rs = rsqrtf(s2*(1.f/96.f) - m*m + 1e-5f);
    const int mt = t >> 4, row = t & 15;
    #pragma unroll
    for (int jj = 0; jj < 12; jj++){
      int k = p*24 + 2*jj;
      float a = (c[2*jj]  -m)*rs*g2[k]   + bb2[k];
      float d = (c[2*jj+1]-m)*rs*g2[k+1] + bb2[k+1];
      int ks = k >> 5, g = (k & 31) >> 3, i = k & 7;
      *(u32*)&xA[(((mt*3 + ks)*64 + g*16 + row)<<3) + i] = pack2(a, d);
    }
  }
  __syncthreads();

  bf16x8 af[3];
  #pragma unroll
  for (int ks = 0; ks < 3; ks++)
    af[ks] = *(const bf16x8*)&xA[((wvM*3 + ks)*64 + ln)*8];

  f32x4 acc2[6];
  #pragma unroll
  for (int j = 0; j < 6; j++) acc2[j] = (f32x4){0.f,0.f,0.f,0.f};

  for (int q = 0; q < 4; q++){
    __syncthreads();
    #pragma unroll
    for (int j = 0; j < 6; j++){
      f32x4 c = (f32x4){0.f,0.f,0.f,0.f};
      #pragma unroll
      for (int ks = 0; ks < 3; ks++){
        bf16x8 bfv = *(const bf16x8*)(w1m + ((q*18 + j*3 + ks)*64 + ln)*4);
        c = __builtin_amdgcn_mfma_f32_16x16x32_bf16(af[ks], bfv, c, 0, 0, 0);
      }
      const float bv = b1[q*96 + j*16 + colv];
      const int kq = j*16 + colv;
      const int ks2 = kq >> 5, gg = (kq & 31) >> 3, ii = kq & 7;
      u16* hdst = &hA[(((wvM*3 + ks2)*64 + gg*16)<<3) + ii];
      #pragma unroll
      for (int r = 0; r < 4; r++){
        int rowh = rgrp*4 + r;
        hdst[rowh*8] = f2bf(gelu(c[r] + bv));
      }
    }
    __syncthreads();

    bf16x8 hf[3];
    #pragma unroll
    for (int ks = 0; ks < 3; ks++)
      hf[ks] = *(const bf16x8*)&hA[((wvM*3 + ks)*64 + ln)*8];
    #pragma unroll
    for (int j = 0; j < 6; j++){
      #pragma unroll
      for (int ks = 0; ks < 3; ks++){
        bf16x8 bfv = *(const bf16x8*)(w2m + ((q*18 + j*3 + ks)*64 + ln)*4);
        acc2[j] = __builtin_amdgcn_mfma_f32_16x16x32_bf16(hf[ks], bfv, acc2[j], 0, 0, 0);
      }
    }
  }

  #pragma unroll
  for (int j = 0; j < 6; j++){
    const int oc = j*16 + colv;
    const float bv = b2[oc];
    #pragma unroll
    for (int r = 0; r < 4; r++){
      size_t tok = t0 + wvM*16 + rgrp*4 + r;
      x2o[tok*96 + oc] = acc2[j][r] + bv + bf2f(x1[tok*96 + oc]);
    }
  }
}

// ---------------------------------------------------------------------------
// K2b: MLP, staged fallback (R15-verified).
// ---------------------------------------------------------------------------
__global__ __launch_bounds__(256,2) void mlp_stage_k(
    const u16* __restrict__ x1, const float* __restrict__ w1, const float* __restrict__ b1,
    const float* __restrict__ w2, const float* __restrict__ b2,
    const float* __restrict__ g2, const float* __restrict__ bb2,
    float* __restrict__ x2o)
{
  __shared__ __align__(16) u16 xA [4*3*64*8];
  __shared__ __align__(16) u16 hA [4*3*64*8];
  __shared__ __align__(16) u16 w1f[6*3*64*8];
  __shared__ __align__(16) u16 w2f[6*3*64*8];
  const int tid = threadIdx.x;
  const size_t t0 = (size_t)blockIdx.x * 64;
  const int wvM = tid >> 6;
  const int ln  = tid & 63;
  const int colv = ln & 15, rgrp = ln >> 4;

  {
    const int t = tid >> 2, p = tid & 3;
    const u16* xr = x1 + (t0 + t)*96 + p*24;
    float c[24];
    #pragma unroll
    for (int q = 0; q < 3; q++){
      uint4 v = ((const uint4*)xr)[q];
      c[q*8+0]=lo16(v.x); c[q*8+1]=hi16(v.x);
      c[q*8+2]=lo16(v.y); c[q*8+3]=hi16(v.y);
      c[q*8+4]=lo16(v.z); c[q*8+5]=hi16(v.z);
      c[q*8+6]=lo16(v.w); c[q*8+7]=hi16(v.w);
    }
    float s = 0.f, s2 = 0.f;
    #pragma unroll
    for (int j = 0; j < 24; j++){ s += c[j]; s2 += c[j]*c[j]; }
    s  += __shfl_xor(s, 1);  s  += __shfl_xor(s, 2);
    s2 += __shfl_xor(s2, 1); s2 += __shfl_xor(s2, 2);
    float m = s*(1.f/96.f);
    float rs = rsqrtf(s2*(1.f/96.f) - m*m + 1e-5f);
    const int mt = t >> 4, row = t & 15;
    #pragma unroll
    for (int jj = 0; jj < 12; jj++){
      int k = p*24 + 2*jj;
      float a = (c[2*jj]  -m)*rs*g2[k]   + bb2[k];
      float d = (c[2*jj+1]-m)*rs*g2[k+1] + bb2[k+1];
      int ks = k >> 5, g = (k & 31) >> 3, i = k & 7;
      *(u32*)&xA[(((mt*3 + ks)*64 + g*16 + row)<<3) + i] = pack2(a, d);
    }
  }

  f32x4 acc2[6];
  #pragma unroll
  for (int j = 0; j < 6; j++) acc2[j] = (f32x4){0.f,0.f,0.f,0.f};

  for (int q = 0; q < 4; q++){
    __syncthreads();
    for (int e = tid; e < 4608; e += 256){
      int n = e/48, cp = e - (e/48)*48, k = cp*2;
      int ks = k >> 5, g = (k & 31) >> 3, i = k & 7;
      int fidx = ((((n>>4)*3 + ks)*64 + g*16 + (n&15))<<3) + i;
      {
        const float* s = w1 + (size_t)(q*96 + n)*96 + k;
        *(u32*)&w1f[fidx] = pack2(s[0], s[1]);
      }
      {
        const float* s = w2 + (size_t)n*384 + q*96 + k;
        *(u32*)&w2f[fidx] = pack2(s[0], s[1]);
      }
    }
    __syncthreads();

    bf16x8 af[3];
    #pragma unroll
    for (int ks = 0; ks < 3; ks++)
      af[ks] = *(const bf16x8*)&xA[((wvM*3 + ks)*64 + ln)*8];
    #pragma unroll
    for (int j = 0; j < 6; j++){
      f32x4 c = (f32x4){0.f,0.f,0.f,0.f};
      #pragma unroll
      for (int ks = 0; ks < 3; ks++){
        bf16x8 bfv = *(const bf16x8*)&w1f[((j*3 + ks)*64 + ln)*8];
        c = __builtin_amdgcn_mfma_f32_16x16x32_bf16(af[ks], bfv, c, 0, 0, 0);
      }
      const float bv = b1[q*96 + j*16 + colv];
      const int kq = j*16 + colv;
      const int ks2 = kq >> 5, gg = (kq & 31) >> 3, ii = kq & 7;
      u16* hdst = &hA[(((wvM*3 + ks2)*64 + gg*16)<<3) + ii];
      #pragma unroll
      for (int r = 0; r < 4; r++){
        int rowh = rgrp*4 + r;
        hdst[rowh*8] = f2bf(gelu(c[r] + bv));
      }
    }
    __syncthreads();

    bf16x8 hf[3];
    #pragma unroll
    for (int ks = 0; ks < 3; ks++)
      hf[ks] = *(const bf16x8*)&hA[((wvM*3 + ks)*64 + ln)*8];
    #pragma unroll
    for (int j = 0; j < 6; j++){
      #pragma unroll
      for (int ks = 0; ks < 3; ks++){
        bf16x8 bfv = *(const bf16x8*)&w2f[((j*3 + ks)*64 + ln)*8];
        acc2[j] = __builtin_amdgcn_mfma_f32_16x16x32_bf16(hf[ks], bfv, acc2[j], 0, 0, 0);
      }
    }
  }

  #pragma unroll
  for (int j = 0; j < 6; j++){
    const int oc = j*16 + colv;
    const float bv = b2[oc];
    #pragma unroll
    for (int r = 0; r < 4; r++){
      size_t tok = t0 + wvM*16 + rgrp*4 + r;
      x2o[tok*96 + oc] = acc2[j][r] + bv + bf2f(x1[tok*96 + oc]);
    }
  }
}

// ---------------------------------------------------------------------------
// K3: MFMA implicit-GEMM 3x3 conv (R16-verified).
// ---------------------------------------------------------------------------
template<int DIL, bool LN3, bool FINAL, bool WD>
__global__ __launch_bounds__(256,4) void convm_k(
    const void* __restrict__ srcv, const u32* __restrict__ wpk,
    const float* __restrict__ wOIHW,
    const float* __restrict__ cb, const float* __restrict__ bng, const float* __restrict__ bnb,
    const float* __restrict__ bnm, const float* __restrict__ bnv,
    const float* __restrict__ g3, const float* __restrict__ b3,
    const float* resid, void* dstv)
{
  constexpr int SY = 8 + 2*DIL, SX = 8 + 2*DIL, NPIX = SY*SX;
  __shared__ __align__(16) u16 inT[NPIX*104];
  const int tid = threadIdx.x;
  const int bx = blockIdx.x*8, by = blockIdx.y*8, b = blockIdx.z;
  const int gy0 = by - DIL, gx0 = bx - DIL;

  for (int e = tid; e < NPIX*48; e += 256){
    int p = e/48, c2 = e - (e/48)*48;
    int y = p/SX, xx = p - (p/SX)*SX;
    int gy = gy0+y, gx = gx0+xx;
    u32 v = 0;
    if (gy >= 0 && gy < 224 && gx >= 0 && gx < 224){
      size_t idx = ((size_t)((b*224+gy)*224+gx))*96 + c2*2;
      if (LN3){
        float2 rd = *(const float2*)((const float*)srcv + idx);
        v = pack2(rd.x, rd.y);
      } else {
        v = *(const u32*)((const u16*)srcv + idx);
      }
    }
    *(u32*)&inT[p*104 + c2*2] = v;
  }
  __syncthreads();
  if (LN3){
    if (tid < 2*NPIX){
      const int p = tid >> 1, half = tid & 1;
      int y = p/SX, xx = p - (p/SX)*SX;
      int gy = gy0+y, gx = gx0+xx;
      if (gy >= 0 && gy < 224 && gx >= 0 && gx < 224){
        u32* row = (u32*)&inT[p*104] + half*24;
        float c[48];
        #pragma unroll
        for (int i = 0; i < 24; i++){ u32 v = row[i]; c[2*i] = lo16(v); c[2*i+1] = hi16(v); }
        float s = 0.f, s2 = 0.f;
        #pragma unroll
        for (int i = 0; i < 48; i++){ s += c[i]; s2 += c[i]*c[i]; }
        s  += __shfl_xor(s, 1);
        s2 += __shfl_xor(s2, 1);
        float m = s*(1.f/96.f);
        float rs = rsqrtf(s2*(1.f/96.f) - m*m + 1e-5f);
        const int cbase = half*48;
        #pragma unroll
        for (int i = 0; i < 24; i++){
          float a = (c[2*i]  -m)*rs*g3[cbase+2*i]   + b3[cbase+2*i];
          float d = (c[2*i+1]-m)*rs*g3[cbase+2*i+1] + b3[cbase+2*i+1];
          row[i] = pack2(a, d);
        }
      }
    }
    __syncthreads();
  }

  const int wvM = tid >> 6, ln = tid & 63;
  const int colv = ln & 15, rgrp = ln >> 4;
  const int arow = ln & 15;
  const int aoy = wvM*2 + (arow >> 3), aox = arow & 7;

  f32x4 acc[6];
  #pragma unroll
  for (int j = 0; j < 6; j++) acc[j] = (f32x4){0.f,0.f,0.f,0.f};

  if constexpr (WD){
    #pragma unroll 3
    for (int tap = 0; tap < 9; tap++){
      const int ky = tap/3, kx = tap - (tap/3)*3;
      const int p_in = (aoy + ky*DIL)*SX + aox + kx*DIL;
      bf16x8 af[3];
      #pragma unroll
      for (int ks = 0; ks < 3; ks++)
        af[ks] = *(const bf16x8*)&inT[p_in*104 + ks*32 + rgrp*8];
      const u32* wt = wpk + tap*4608;
      #pragma unroll
      for (int j = 0; j < 6; j++){
        #pragma unroll
        for (int ks = 0; ks < 3; ks++){
          bf16x8 bfv = *(const bf16x8*)(wt + ((j*3 + ks)*64 + ln)*4);
          acc[j] = __builtin_amdgcn_mfma_f32_16x16x32_bf16(af[ks], bfv, acc[j], 0, 0, 0);
        }
      }
    }
  } else {
    __shared__ __align__(16) u32 wfr[4608];
    for (int tap = 0; tap < 9; tap++){
      const int ky = tap/3, kx = tap - (tap/3)*3;
      __syncthreads();
      for (int e = tid; e < 4608; e += 256){
        int jk = e >> 8, lane = (e >> 2) & 63, q = e & 3;
        int j = jk/3, ks = jk - j*3;
        int n = j*16 + (lane & 15);
        int k = ks*32 + (lane >> 4)*8 + 2*q;
        wfr[e] = pack2(wOIHW[(n*96 + k)*9 + tap], wOIHW[(n*96 + k + 1)*9 + tap]);
      }
      __syncthreads();
      const int p_in = (aoy + ky*DIL)*SX + aox + kx*DIL;
      bf16x8 af[3];
      #pragma unroll
      for (int ks = 0; ks < 3; ks++)
        af[ks] = *(const bf16x8*)&inT[p_in*104 + ks*32 + rgrp*8];
      #pragma unroll
      for (int j = 0; j < 6; j++){
        #pragma unroll
        for (int ks = 0; ks < 3; ks++){
          bf16x8 bfv = *(const bf16x8*)((const u16*)wfr + ((j*3 + ks)*64 + ln)*8);
          acc[j] = __builtin_amdgcn_mfma_f32_16x16x32_bf16(af[ks], bfv, acc[j], 0, 0, 0);
        }
      }
    }
  }

  #pragma unroll
  for (int j = 0; j < 6; j++){
    const int oc = j*16 + colv;
    const float sc = bng[oc]*rsqrtf(bnv[oc]+1e-5f);
    const float mm = bnm[oc], bb = bnb[oc], cbv = cb[oc];
    #pragma unroll
    for (int r = 0; r < 4; r++){
      const int rowm = rgrp*4 + r;
      const int gy = by + wvM*2 + (rowm >> 3), gx = bx + (rowm & 7);
      size_t idx = ((size_t)((b*224+gy)*224+gx))*96 + oc;
      float t = (acc[j][r] + cbv - mm)*sc + bb;
      float o = gelu(t);
      if (FINAL){
        ((float*)dstv)[idx] = o + resid[idx];
      } else {
        ((u16*)dstv)[idx] = f2bf(o);
      }
    }
  }
}

// ---------------------------------------------------------------------------
extern "C" void kernel_launch(void* const* d_in, const int* in_sizes, int n_in,
                              void* d_out, int out_size, void* d_ws, size_t ws_size,
                              hipStream_t stream)
{
  const float* x    = (const float*)d_in[0];
  const float* ndwi = (const float*)d_in[1];
  const float* n1g  = (const float*)d_in[2];
  const float* n1b  = (const float*)d_in[3];
  const float* qkvw = (const float*)d_in[4];
  const float* qkvb = (const float*)d_in[5];
  const float* projw= (const float*)d_in[6];
  const float* projb= (const float*)d_in[7];
  const float* rpbt = (const float*)d_in[8];
  const float* n2g  = (const float*)d_in[9];
  const float* n2b  = (const float*)d_in[10];
  const float* w1   = (const float*)d_in[11];
  const float* b1   = (const float*)d_in[12];
  const float* w2   = (const float*)d_in[13];
  const float* b2   = (const float*)d_in[14];
  const float* n3g  = (const float*)d_in[15];
  const float* n3b  = (const float*)d_in[16];
  const float* c1w  = (const float*)d_in[17];
  const float* c1b  = (const float*)d_in[18];
  const float* bn1g = (const float*)d_in[19];
  const float* bn1b = (const float*)d_in[20];
  const float* bn1m = (const float*)d_in[21];
  const float* bn1v = (const float*)d_in[22];
  const float* c2w  = (const float*)d_in[23];
  const float* c2b  = (const float*)d_in[24];
  const float* bn2g = (const float*)d_in[25];
  const float* bn2b = (const float*)d_in[26];
  const float* bn2m = (const float*)d_in[27];
  const float* bn2v = (const float*)d_in[28];

  int B = out_size / (224*224*96);
  if (B < 1 || B > 64) B = 4;
  const size_t elems = (size_t)B*224*224*96;

  u16*   wsA = (u16*)d_ws;
  u32*   w8q = (u32*)d_out;
  u32*   w8p = w8q + 13824;
  float* xo  = (float*)d_out;
  u32*   wcv = nullptr;
  u32*   wm  = nullptr;
  if (ws_size >= elems*sizeof(u16) + 82944*sizeof(u32))
    wcv = (u32*)(wsA + elems);
  if (ws_size >= elems*sizeof(u16) + (82944 + 36864)*sizeof(u32))
    wm = wcv + 82944;

  wprep_k<<<dim3(72), dim3(256), 0, stream>>>(qkvw, projw, w8q, w8p);
  if (wcv) wprep_cv<<<dim3(324), dim3(256), 0, stream>>>(c1w, c2w, wcv);
  if (wm)  wprep_m<<<dim3(144), dim3(256), 0, stream>>>(w1, w2, wm);
  attn_k<<<dim3(B*1024), dim3(512), 0, stream>>>(x, ndwi, n1g, n1b, w8q, qkvb, w8p, projb, rpbt, wsA);
  if (wm)
    mlp_direct_k<<<dim3(B*784), dim3(256), 0, stream>>>(wsA, wm, b1, b2, n2g, n2b, xo);
  else
    mlp_stage_k<<<dim3(B*784), dim3(256), 0, stream>>>(wsA, w1, b1, w2, b2, n2g, n2b, xo);
  if (wcv){
    convm_k<1,true ,false,true ><<<dim3(28,28,B), dim3(256), 0, stream>>>(
        xo,  wcv,        c1w, c1b, bn1g, bn1b, bn1m, bn1v, n3g, n3b, nullptr, wsA);
    convm_k<2,false,true ,true ><<<dim3(28,28,B), dim3(256), 0, stream>>>(
        wsA, wcv+41472,  c2w, c2b, bn2g, bn2b, bn2m, bn2v, nullptr, nullptr, xo, xo);
  } else {
    convm_k<1,true ,false,false><<<dim3(28,28,B), dim3(256), 0, stream>>>(
        xo,  nullptr,    c1w, c1b, bn1g, bn1b, bn1m, bn1v, n3g, n3b, nullptr, wsA);
    convm_k<2,false,true ,false><<<dim3(28,28,B), dim3(256), 0, stream>>>(
        wsA, nullptr,    c2w, c2b, bn2g, bn2b, bn2m, bn2v, nullptr, nullptr, xo, xo);
  }
}